// Round 7
// baseline (250.104 us; speedup 1.0000x reference)
//
#include <hip/hip_runtime.h>

typedef unsigned short u16;
typedef unsigned int u32;
typedef __attribute__((ext_vector_type(8))) __bf16 bf16x8;
typedef __attribute__((ext_vector_type(4))) float f32x4;
typedef __attribute__((ext_vector_type(4))) u32 u32x4;

// B=2, S=2048, DIM=1024, H=16, HD=64

static __device__ __forceinline__ u16 f2bf(float f) {
  unsigned u = __builtin_bit_cast(unsigned, f);
  u += 0x7FFFu + ((u >> 16) & 1u);
  return (u16)(u >> 16);
}
static __device__ __forceinline__ float bf2f(u16 v) {
  return __builtin_bit_cast(float, (u32)v << 16);
}

static __device__ __forceinline__ void gload_lds16(const void* g, void* l) {
  __builtin_amdgcn_global_load_lds(
      (const __attribute__((address_space(1))) unsigned int*)g,
      (__attribute__((address_space(3))) unsigned int*)l, 16, 0, 0);
}

// One kernel converts x, W_qkv, W_o (fp32 -> bf16). 2097152 float4 total.
__global__ __launch_bounds__(256) void cvt_all(const float* __restrict__ x,
                                               const float* __restrict__ wq,
                                               const float* __restrict__ wo,
                                               u16* __restrict__ xb,
                                               u16* __restrict__ wqb,
                                               u16* __restrict__ wob) {
  int i = blockIdx.x * 256 + threadIdx.x;
  const float* src;
  u16* dst;
  int off;
  if (i < 1048576) {
    src = x; dst = xb; off = i;
  } else if (i < 1048576 + 786432) {
    src = wq; dst = wqb; off = i - 1048576;
  } else {
    src = wo; dst = wob; off = i - 1835008;
  }
  float4 f = ((const float4*)src)[off];
  uint2 o;
  o.x = (unsigned)f2bf(f.x) | ((unsigned)f2bf(f.y) << 16);
  o.y = (unsigned)f2bf(f.z) | ((unsigned)f2bf(f.w) << 16);
  ((uint2*)dst)[off] = o;
}

// QKV GEMM. C[m,n] = sum_k A[m,k]*B[n,k]. 128x128 tile, BK=64, single 32KB
// buffer pair, two __syncthreads per K-step (best structure for this shape).
// q (pre-scaled by 0.125*log2e) / k scattered to (b,h,s,hd); V blocks
// (n0>=2048) transposed through LDS and stored as TILED V^T:
// v2[bh][tile=s/64][hd][64 keys] — 4KB contiguous per 64-key tile. Round-7:
// this kills the 4KB-stride channel-camping that doubled HBM fetch when attn
// read the flat (b,h,hd,s) V^T directly (round-6 evidence: FETCH 37->74MB).
__global__ __launch_bounds__(256, 2) void gemm_qkv(
    const u16* __restrict__ A, const u16* __restrict__ Bm, int K,
    u16* __restrict__ qo, u16* __restrict__ ko, u16* __restrict__ vo) {
  __shared__ __align__(16) u16 SH[2][128 * 64];  // A-tile, B-tile; reused for V^T
  const int tid = threadIdx.x;
  const int lane = tid & 63, w = tid >> 6;
  const int wr = w >> 1, wc = w & 1;
  // T1: XCD-aware bijective swizzle (nwg % 8 == 0).
  const int hfl = blockIdx.y * gridDim.x + blockIdx.x;
  const int qq = (gridDim.x * gridDim.y) >> 3;
  const int wid = (hfl & 7) * qq + (hfl >> 3);
  const int m0 = (wid % gridDim.y) * 128;
  const int n0 = (wid / gridDim.y) * 128;
  const int c16 = lane >> 4, r16 = lane & 15;

  const f32x4 zero4 = {0.f, 0.f, 0.f, 0.f};
  f32x4 acc[4][4];
#pragma unroll
  for (int r = 0; r < 4; ++r)
#pragma unroll
    for (int c = 0; c < 4; ++c) acc[r][c] = zero4;

  const int nk = K >> 6;

  // LDS tile: [128 rows][64 cols] bf16, byte ^= ((row&7)<<4) swizzle.
  // global_load_lds writes linearly -> pre-swizzled SOURCE (rule #21).
  auto stage = [&](int kt) {
#pragma unroll
    for (int i = 0; i < 4; ++i) {
      const int chunk = w * 4 + i;
      const int lb = chunk * 1024 + lane * 16;
      const int row = lb >> 7;
      const int rb = (lb & 127) ^ ((row & 7) << 4);
      gload_lds16(A + (size_t)(m0 + row) * K + kt * 64 + (rb >> 1),
                  (char*)&SH[0][0] + chunk * 1024);
      gload_lds16(Bm + (size_t)(n0 + row) * K + kt * 64 + (rb >> 1),
                  (char*)&SH[1][0] + chunk * 1024);
    }
  };

  stage(0);
  __syncthreads();
  for (int kt = 0; kt < nk; ++kt) {
#pragma unroll
    for (int ks = 0; ks < 2; ++ks) {
      bf16x8 af[4], bfv[4];
#pragma unroll
      for (int r = 0; r < 4; ++r) {
        const int ra = wr * 64 + r * 16 + r16;
        af[r] = *(const bf16x8*)((const char*)&SH[0][0] +
                ((ra * 128 + ks * 64 + c16 * 16) ^ ((ra & 7) << 4)));
        const int rbn = wc * 64 + r * 16 + r16;
        bfv[r] = *(const bf16x8*)((const char*)&SH[1][0] +
                ((rbn * 128 + ks * 64 + c16 * 16) ^ ((rbn & 7) << 4)));
      }
#pragma unroll
      for (int r = 0; r < 4; ++r)
#pragma unroll
        for (int c = 0; c < 4; ++c)
          acc[r][c] = __builtin_amdgcn_mfma_f32_16x16x32_bf16(
              af[r], bfv[c], acc[r][c], 0, 0, 0);
    }
    __syncthreads();
    if (kt + 1 < nk) stage(kt + 1);
    __syncthreads();
  }

  if (n0 < 2048) {
    // q/k scatter: 16 lanes write 32B contiguous (sector-efficient)
    const float qs = (n0 < 1024) ? 0.18033688f : 1.0f;  // 0.125*log2e for q
    u16* dst0 = (n0 < 1024) ? qo : ko;
#pragma unroll
    for (int r = 0; r < 4; ++r)
#pragma unroll
      for (int c = 0; c < 4; ++c)
#pragma unroll
        for (int b = 0; b < 4; ++b) {
          const int row = m0 + wr * 64 + r * 16 + 4 * c16 + b;
          const int col = n0 + wc * 64 + c * 16 + r16;
          const int hh = (col & 1023) >> 6, hd = col & 63;
          const int bi = row >> 11, s = row & 2047;
          dst0[((size_t)(bi * 16 + hh) * 2048 + s) * 64 + hd] =
              f2bf(acc[r][c][b] * qs);
        }
  } else {
    // V block: transpose 128x128 through LDS (free after K-loop), then
    // store tiled V^T: v2[bh][s/64][hd][64] — 16B contiguous chunks.
#pragma unroll
    for (int r = 0; r < 4; ++r)
#pragma unroll
      for (int c = 0; c < 4; ++c)
#pragma unroll
        for (int b = 0; b < 4; b += 2) {
          const int row_l = wr * 64 + r * 16 + 4 * c16 + b;
          const int col_l = wc * 64 + c * 16 + r16;
          const u32 val = (u32)f2bf(acc[r][c][b]) |
                          ((u32)f2bf(acc[r][c][b + 1]) << 16);
          *(u32*)((char*)&SH[0][0] +
                  ((col_l * 256 + (row_l >> 1) * 4) ^ ((col_l & 7) << 4))) = val;
        }
    __syncthreads();
    const int col_l = tid >> 1, half = tid & 1;
    const int hh = (n0 - 2048 + col_l) >> 6, hd = (n0 - 2048 + col_l) & 63;
    const int bi = m0 >> 11;
    const int tile = ((m0 & 2047) >> 6) + half;  // 64-key tile index
    u16* dst = vo + (size_t)(bi * 16 + hh) * 131072 + tile * 4096 + hd * 64;
#pragma unroll
    for (int j = 0; j < 8; ++j) {
      const uint4 v4 = *(const uint4*)((const char*)&SH[0][0] +
          (col_l * 256 + ((half * 128 + j * 16) ^ ((col_l & 7) << 4))));
      *(uint4*)(dst + j * 8) = v4;
    }
  }
}

// Output-projection GEMM (fp32 out): 64x128 tile, 2 waves, LDS 24KB.
// Grid (8,64) = 512 blocks = 2/CU co-resident; ~11us (860GF), near floor
// for this latency-bound shape.
__global__ __launch_bounds__(128, 3) void gemm_proj(
    const u16* __restrict__ A, const u16* __restrict__ Bm, int K, int N,
    float* __restrict__ fo) {
  __shared__ __align__(16) u16 Asm[64 * 64];    // 8KB
  __shared__ __align__(16) u16 Bsm[128 * 64];   // 16KB
  const int tid = threadIdx.x;
  const int lane = tid & 63, w = tid >> 6;      // 2 waves
  const int hfl = blockIdx.y * gridDim.x + blockIdx.x;
  const int qq = (gridDim.x * gridDim.y) >> 3;
  const int wid = (hfl & 7) * qq + (hfl >> 3);
  const int m0 = (wid % gridDim.y) * 64;
  const int n0 = (wid / gridDim.y) * 128;
  const int c16 = lane >> 4, r16 = lane & 15;

  const f32x4 zero4 = {0.f, 0.f, 0.f, 0.f};
  f32x4 acc[4][4];
#pragma unroll
  for (int r = 0; r < 4; ++r)
#pragma unroll
    for (int c = 0; c < 4; ++c) acc[r][c] = zero4;

  const int nk = K >> 6;

  auto stage = [&](int kt) {
#pragma unroll
    for (int i = 0; i < 4; ++i) {
      const int chunk = w * 4 + i;              // 8 chunks of 1KB (A)
      const int lb = chunk * 1024 + lane * 16;
      const int row = lb >> 7;
      const int rb = (lb & 127) ^ ((row & 7) << 4);
      gload_lds16(A + (size_t)(m0 + row) * K + kt * 64 + (rb >> 1),
                  (char*)&Asm[0] + chunk * 1024);
    }
#pragma unroll
    for (int i = 0; i < 8; ++i) {
      const int chunk = w * 8 + i;              // 16 chunks of 1KB (B)
      const int lb = chunk * 1024 + lane * 16;
      const int row = lb >> 7;
      const int rb = (lb & 127) ^ ((row & 7) << 4);
      gload_lds16(Bm + (size_t)(n0 + row) * K + kt * 64 + (rb >> 1),
                  (char*)&Bsm[0] + chunk * 1024);
    }
  };

  stage(0);
  __syncthreads();
  for (int kt = 0; kt < nk; ++kt) {
#pragma unroll
    for (int ks = 0; ks < 2; ++ks) {
      bf16x8 af[4], bfv[4];
#pragma unroll
      for (int r = 0; r < 4; ++r) {
        const int ra = r * 16 + r16;            // rows 0..63 (full M-tile)
        af[r] = *(const bf16x8*)((const char*)&Asm[0] +
                ((ra * 128 + ks * 64 + c16 * 16) ^ ((ra & 7) << 4)));
        const int rbn = w * 64 + r * 16 + r16;  // own 64-col half of B
        bfv[r] = *(const bf16x8*)((const char*)&Bsm[0] +
                ((rbn * 128 + ks * 64 + c16 * 16) ^ ((rbn & 7) << 4)));
      }
#pragma unroll
      for (int r = 0; r < 4; ++r)
#pragma unroll
        for (int c = 0; c < 4; ++c)
          acc[r][c] = __builtin_amdgcn_mfma_f32_16x16x32_bf16(
              af[r], bfv[c], acc[r][c], 0, 0, 0);
    }
    __syncthreads();
    if (kt + 1 < nk) stage(kt + 1);
    __syncthreads();
  }

#pragma unroll
  for (int r = 0; r < 4; ++r)
#pragma unroll
    for (int c = 0; c < 4; ++c)
#pragma unroll
      for (int b = 0; b < 4; ++b) {
        const int row = m0 + r * 16 + 4 * c16 + b;
        const int col = n0 + w * 64 + c * 16 + r16;
        fo[(size_t)row * N + col] = acc[r][c][b];
      }
}

// Flash attention, ALiBi + causal. Round-7: K double-buffered in LDS
// (16.4KB -> 8 blocks/CU, 100% static occupancy, launch_bounds(256,8);
// round-6 compiled this structure at 48 VGPR), V read directly from the
// TILED V^T layout (4KB contiguous per 64-key tile — fixes round-6's
// 4KB-stride channel camping that doubled FETCH and stalled PV). vf loads
// issued at iteration top; ~200cy L2 latency hides under QK^T+softmax.
// Fragment values and per-q-row accumulation order identical to round-3
// -> bit-identical numerics.
__global__ __launch_bounds__(256, 8) void attn_part(const u16* __restrict__ qb,
                                                    const u16* __restrict__ kb,
                                                    const u16* __restrict__ vtb,
                                                    u16* __restrict__ ob,
                                                    u16* __restrict__ Op,
                                                    float* __restrict__ ml) {
  __shared__ __align__(16) u16 Kl[2][64 * 64];  // [key][hd], swizzled, 16KB

  const int tid = threadIdx.x;
  const int lane = tid & 63, w = tid >> 6;
  const int lo = lane & 15, hi = lane >> 4;
  const int yb = blockIdx.y;
  const int h = 15 - (yb >> 1), bi = yb & 1;   // LPT: heavy heads first
  const int bh = bi * 16 + h;
  const int y = blockIdx.x;                     // work item; XCD = x%8

  int qt, t0, t1, slot = 0;
  bool part;
  if (y < 16) {           // chunk1 of qt = 31-y  (len 9..16, has diag)
    qt = 31 - y;
    const int T = qt + 1;
    t0 = T >> 1; t1 = T; part = true;
    slot = bh * 32 + (qt - 16) * 2 + 1;
  } else if (y < 32) {    // chunk0 of qt = 47-y  (len 8..16)
    qt = 47 - y;
    const int T = qt + 1;
    t0 = 0; t1 = T >> 1; part = true;
    slot = bh * 32 + (qt - 16) * 2;
  } else {                // direct qt = 47-y     (len 1..16)
    qt = 47 - y;
    t0 = 0; t1 = qt + 1; part = false;
  }

  const int q0 = qt * 64;
  const float slope2 = exp2f(-0.5f * (float)(h + 1)) * 1.44269504089f;
  const float s64 = slope2 * 64.f;

  const int Dt = min(32, (int)ceilf(34.f / s64));
  t1 = min(t1, Dt);

  if (part && t0 >= t1) {
#pragma unroll
    for (int g = 0; g < 4; ++g)
#pragma unroll
      for (int r = 0; r < 4; ++r) {
        const int sl = w * 16 + 4 * hi + r;
        Op[(size_t)slot * 4096 + sl * 64 + g * 16 + lo] = 0;
      }
    if (hi == 0) ml[slot * 64 + w * 16 + lo] = 0.f;
    return;
  }

  const u16* __restrict__ Q = qb + (size_t)bh * 131072;
  const u16* __restrict__ Kp = kb + (size_t)bh * 131072;
  const u16* __restrict__ Vp = vtb + (size_t)bh * 131072;

  auto stageK = [&](int t, int buf) {
#pragma unroll
    for (int i = 0; i < 2; ++i) {
      const int chunk = w * 2 + i;
      const int lb = chunk * 1024 + lane * 16;
      const int row = lb >> 7;
      const int rb = (lb & 127) ^ ((row & 7) << 4);
      gload_lds16(Kp + (size_t)(t * 64 + row) * 64 + (rb >> 1),
                  (char*)&Kl[buf][0] + chunk * 1024);
    }
  };

  bf16x8 qf[2];
  {
    const u16* qsrc = Q + (size_t)(q0 + w * 16 + lo) * 64 + hi * 8;
    qf[0] = *(const bf16x8*)qsrc;
    qf[1] = *(const bf16x8*)(qsrc + 32);
  }

  const f32x4 zero4 = {0.f, 0.f, 0.f, 0.f};
  f32x4 oacc[4];
#pragma unroll
  for (int g = 0; g < 4; ++g) oacc[g] = zero4;
  float lsum = 0.f;

  float KC[4][4];
#pragma unroll
  for (int g = 0; g < 4; ++g)
#pragma unroll
    for (int r = 0; r < 4; ++r)
      KC[g][r] = slope2 * (float)(16 * g + 4 * hi + r);
  float ctv = 0.f;

  stageK(t0, 0);
  __syncthreads();

  for (int t = t0; t < t1; ++t) {
    const int cur = (t - t0) & 1, nxt = cur ^ 1;
    if (t + 1 < t1) stageK(t + 1, nxt);

    // V fragments for tile t from the tiled V^T (4KB contiguous tile;
    // issued early, L2/L1-resident; hidden under QK^T + softmax).
    bf16x8 vf[4][2];
#pragma unroll
    for (int g = 0; g < 4; ++g)
#pragma unroll
      for (int u = 0; u < 2; ++u)
        vf[g][u] = *(const bf16x8*)(Vp + (size_t)t * 4096 +
                                    (g * 16 + lo) * 64 + u * 32 + hi * 8);

    f32x4 st[4];
#pragma unroll
    for (int g = 0; g < 4; ++g) {
#pragma unroll
      for (int r = 0; r < 4; ++r) st[g][r] = ctv - KC[g][r];
#pragma unroll
      for (int ks = 0; ks < 2; ++ks) {
        const int krow = g * 16 + lo;
        const bf16x8 kf = *(const bf16x8*)((const char*)&Kl[cur][0] +
            ((krow * 128 + ks * 64 + hi * 16) ^ ((krow & 7) << 4)));
        st[g] = __builtin_amdgcn_mfma_f32_16x16x32_bf16(kf, qf[ks], st[g], 0, 0, 0);
      }
    }

    if (t == qt) {
#pragma unroll
      for (int g = 0; g < 4; ++g)
#pragma unroll
        for (int r = 0; r < 4; ++r)
          if (g * 16 + 4 * hi + r > w * 16 + lo) st[g][r] = -1e30f;
    }
    float p[4][4];
    float rs = 0.f;
#pragma unroll
    for (int g = 0; g < 4; ++g)
#pragma unroll
      for (int r = 0; r < 4; ++r) {
        p[g][r] = exp2f(st[g][r]);
        rs += p[g][r];
      }
    lsum += rs;

    u32 pk[4][2];
#pragma unroll
    for (int g = 0; g < 4; ++g)
#pragma unroll
      for (int c = 0; c < 2; ++c)
        pk[g][c] = __builtin_amdgcn_perm(
            __builtin_bit_cast(u32, p[g][2 * c + 1]),
            __builtin_bit_cast(u32, p[g][2 * c]), 0x07060302u);

    // P-repack via permlane swaps (round-3 proven lane-exact).
    bf16x8 pA[2];
#pragma unroll
    for (int u = 0; u < 2; ++u) {
      u32 x0 = pk[2 * u][0], x1 = pk[2 * u][1];
      u32 y0 = pk[2 * u + 1][0], y1 = pk[2 * u + 1][1];
      asm("v_permlane32_swap_b32 %0, %1" : "+v"(x0), "+v"(y0));
      asm("v_permlane32_swap_b32 %0, %1" : "+v"(x1), "+v"(y1));
      asm("v_permlane16_swap_b32 %0, %1" : "+v"(x0), "+v"(y0));
      asm("v_permlane16_swap_b32 %0, %1" : "+v"(x1), "+v"(y1));
      u32x4 wv;
      wv.x = x0;
      wv.y = x1;
      wv.z = y0;
      wv.w = y1;
      pA[u] = __builtin_bit_cast(bf16x8, wv);
    }

#pragma unroll
    for (int g = 0; g < 4; ++g) {
#pragma unroll
      for (int u = 0; u < 2; ++u) {
        oacc[g] = __builtin_amdgcn_mfma_f32_16x16x32_bf16(pA[u], vf[g][u],
                                                          oacc[g], 0, 0, 0);
      }
    }

    ctv -= s64;
    __syncthreads();
  }

  lsum += __shfl_xor(lsum, 16, 64);
  lsum += __shfl_xor(lsum, 32, 64);
  const float inv = 1.f / lsum;
  float iv[4];
#pragma unroll
  for (int r = 0; r < 4; ++r) iv[r] = __shfl(inv, 4 * hi + r, 64);

  if (!part) {
#pragma unroll
    for (int g = 0; g < 4; ++g)
#pragma unroll
      for (int r = 0; r < 4; ++r) {
        const int s = q0 + w * 16 + 4 * hi + r;
        const int hd = g * 16 + lo;
        ob[(((size_t)bi * 2048 + s) * 16 + h) * 64 + hd] =
            f2bf(oacc[g][r] * iv[r]);
      }
  } else {
#pragma unroll
    for (int g = 0; g < 4; ++g)
#pragma unroll
      for (int r = 0; r < 4; ++r) {
        const int sl = w * 16 + 4 * hi + r;
        Op[(size_t)slot * 4096 + sl * 64 + g * 16 + lo] =
            f2bf(oacc[g][r] * iv[r]);
      }
    if (hi == 0) ml[slot * 64 + w * 16 + lo] = lsum;
  }
}

// Merge the two chunk partials for q-tiles 16..31 (analytic chunk weights:
// w0 = l0, w1 = l1 * exp2(-slope2*64*t0)). Pruned chunk1: l1 = 0 -> 0.
__global__ __launch_bounds__(256) void attn_comb(const u16* __restrict__ Op,
                                                 const float* __restrict__ ml,
                                                 u16* __restrict__ ob) {
  const int bh = blockIdx.x, q16 = blockIdx.y;
  const int h = bh & 15, bi = bh >> 4;
  const int qt = 16 + q16;
  const int t0c = (qt + 1) >> 1;
  const float slope2 = exp2f(-0.5f * (float)(h + 1)) * 1.44269504089f;
  const float e1 = exp2f(-slope2 * 64.f * (float)t0c);
  const int slot0 = bh * 32 + q16 * 2;
  const int row = threadIdx.x >> 2, c0 = (threadIdx.x & 3) * 16;
  const float l0 = ml[slot0 * 64 + row];
  const float l1 = ml[(slot0 + 1) * 64 + row];
  const float w0 = l0, w1 = l1 * e1;
  const float inv = 1.f / (w0 + w1);
  const float a0 = w0 * inv, a1 = w1 * inv;
  const u16* p0 = Op + (size_t)slot0 * 4096 + row * 64 + c0;
  const u16* p1 = p0 + 4096;
  u32 A0[8], A1[8];
  *(uint4*)&A0[0] = *(const uint4*)p0;
  *(uint4*)&A0[4] = *(const uint4*)(p0 + 8);
  *(uint4*)&A1[0] = *(const uint4*)p1;
  *(uint4*)&A1[4] = *(const uint4*)(p1 + 8);
  const int s = qt * 64 + row;
  u32* dst = (u32*)(ob + (((size_t)bi * 2048 + s) * 16 + h) * 64 + c0);
#pragma unroll
  for (int j = 0; j < 8; ++j) {
    const float e0 = a0 * bf2f((u16)(A0[j] & 0xffffu)) +
                     a1 * bf2f((u16)(A1[j] & 0xffffu));
    const float ee1 = a0 * bf2f((u16)(A0[j] >> 16)) +
                      a1 * bf2f((u16)(A1[j] >> 16));
    dst[j] = (u32)f2bf(e0) | ((u32)f2bf(ee1) << 16);
  }
}

extern "C" void kernel_launch(void* const* d_in, const int* in_sizes, int n_in,
                              void* d_out, int out_size, void* d_ws, size_t ws_size,
                              hipStream_t stream) {
  const float* x = (const float*)d_in[0];     // (2,2048,1024)
  const float* Wqkv = (const float*)d_in[1];  // (3072,1024)
  const float* Wo = (const float*)d_in[2];    // (1024,1024)
  float* out = (float*)d_out;                 // (2,2048,1024) fp32

  // workspace layout (u16 elements)
  u16* xb  = (u16*)d_ws;        // x bf16          4194304  | reused: O partials
  u16* wqb = xb + 4194304;      // W_qkv bf16      3145728  | reused: l partials
  u16* wob = wqb + 3145728;     // W_o bf16        1048576
  u16* qbf = wob + 1048576;     // q (b,h,s,hd), pre-scaled  4194304
  u16* kbf = qbf + 4194304;     // k (b,h,s,hd)    4194304
  u16* vbf = kbf + 4194304;     // v^T tiled (b,h,s/64,hd,64)  4194304
  u16* abf = vbf + 4194304;     // attn out (b,s,h,hd) 4194304

  u16* Op = xb;                 // 1024 slots x 4096 u16 (normalized O, bf16)
  float* ml = (float*)wqb;      // 1024 slots x 64 f32 (l per row)

  cvt_all<<<8192, 256, 0, stream>>>(x, Wqkv, Wo, xb, wqb, wob);

  gemm_qkv<<<dim3(24, 32), 256, 0, stream>>>(xb, wqb, 1024, qbf, kbf, vbf);
  attn_part<<<dim3(48, 32), 256, 0, stream>>>(qbf, kbf, vbf, abf, Op, ml);
  attn_comb<<<dim3(32, 16), 256, 0, stream>>>(Op, ml, abf);
  // 64x128 tile, 512 blocks = 2/CU (fills the machine; W_o L2-resident)
  gemm_proj<<<dim3(8, 64), 128, 0, stream>>>(abf, wob, 1024, 1024, out);
}

// Round 8
// 161.442 us; speedup vs baseline: 1.5492x; 1.5492x over previous
//
#include <hip/hip_runtime.h>

typedef unsigned short u16;
typedef unsigned int u32;
typedef __attribute__((ext_vector_type(8))) __bf16 bf16x8;
typedef __attribute__((ext_vector_type(4))) float f32x4;
typedef __attribute__((ext_vector_type(4))) u32 u32x4;

// B=2, S=2048, DIM=1024, H=16, HD=64

static __device__ __forceinline__ u16 f2bf(float f) {
  unsigned u = __builtin_bit_cast(unsigned, f);
  u += 0x7FFFu + ((u >> 16) & 1u);
  return (u16)(u >> 16);
}
static __device__ __forceinline__ float bf2f(u16 v) {
  return __builtin_bit_cast(float, (u32)v << 16);
}

static __device__ __forceinline__ void gload_lds16(const void* g, void* l) {
  __builtin_amdgcn_global_load_lds(
      (const __attribute__((address_space(1))) unsigned int*)g,
      (__attribute__((address_space(3))) unsigned int*)l, 16, 0, 0);
}

// One kernel converts x, W_qkv, W_o (fp32 -> bf16). 2097152 float4 total.
__global__ __launch_bounds__(256) void cvt_all(const float* __restrict__ x,
                                               const float* __restrict__ wq,
                                               const float* __restrict__ wo,
                                               u16* __restrict__ xb,
                                               u16* __restrict__ wqb,
                                               u16* __restrict__ wob) {
  int i = blockIdx.x * 256 + threadIdx.x;
  const float* src;
  u16* dst;
  int off;
  if (i < 1048576) {
    src = x; dst = xb; off = i;
  } else if (i < 1048576 + 786432) {
    src = wq; dst = wqb; off = i - 1048576;
  } else {
    src = wo; dst = wob; off = i - 1835008;
  }
  float4 f = ((const float4*)src)[off];
  uint2 o;
  o.x = (unsigned)f2bf(f.x) | ((unsigned)f2bf(f.y) << 16);
  o.y = (unsigned)f2bf(f.z) | ((unsigned)f2bf(f.w) << 16);
  ((uint2*)dst)[off] = o;
}

// QKV GEMM. C[m,n] = sum_k A[m,k]*B[n,k]. 128x128 tile, BK=64, single 32KB
// buffer pair, two __syncthreads per K-step (best structure for this shape).
// q (pre-scaled by 0.125*log2e) / k scattered to (b,h,s,hd); V blocks
// (n0>=2048) transposed through LDS and stored as TILED V^T:
// v2[bh][tile=s/64][hd][64 keys] — 4KB contiguous per 64-key tile (kills
// the 4KB-stride channel camping seen in round 6: FETCH 37->74MB).
__global__ __launch_bounds__(256, 2) void gemm_qkv(
    const u16* __restrict__ A, const u16* __restrict__ Bm, int K,
    u16* __restrict__ qo, u16* __restrict__ ko, u16* __restrict__ vo) {
  __shared__ __align__(16) u16 SH[2][128 * 64];  // A-tile, B-tile; reused for V^T
  const int tid = threadIdx.x;
  const int lane = tid & 63, w = tid >> 6;
  const int wr = w >> 1, wc = w & 1;
  // T1: XCD-aware bijective swizzle (nwg % 8 == 0).
  const int hfl = blockIdx.y * gridDim.x + blockIdx.x;
  const int qq = (gridDim.x * gridDim.y) >> 3;
  const int wid = (hfl & 7) * qq + (hfl >> 3);
  const int m0 = (wid % gridDim.y) * 128;
  const int n0 = (wid / gridDim.y) * 128;
  const int c16 = lane >> 4, r16 = lane & 15;

  const f32x4 zero4 = {0.f, 0.f, 0.f, 0.f};
  f32x4 acc[4][4];
#pragma unroll
  for (int r = 0; r < 4; ++r)
#pragma unroll
    for (int c = 0; c < 4; ++c) acc[r][c] = zero4;

  const int nk = K >> 6;

  // LDS tile: [128 rows][64 cols] bf16, byte ^= ((row&7)<<4) swizzle.
  // global_load_lds writes linearly -> pre-swizzled SOURCE (rule #21).
  auto stage = [&](int kt) {
#pragma unroll
    for (int i = 0; i < 4; ++i) {
      const int chunk = w * 4 + i;
      const int lb = chunk * 1024 + lane * 16;
      const int row = lb >> 7;
      const int rb = (lb & 127) ^ ((row & 7) << 4);
      gload_lds16(A + (size_t)(m0 + row) * K + kt * 64 + (rb >> 1),
                  (char*)&SH[0][0] + chunk * 1024);
      gload_lds16(Bm + (size_t)(n0 + row) * K + kt * 64 + (rb >> 1),
                  (char*)&SH[1][0] + chunk * 1024);
    }
  };

  stage(0);
  __syncthreads();
  for (int kt = 0; kt < nk; ++kt) {
#pragma unroll
    for (int ks = 0; ks < 2; ++ks) {
      bf16x8 af[4], bfv[4];
#pragma unroll
      for (int r = 0; r < 4; ++r) {
        const int ra = wr * 64 + r * 16 + r16;
        af[r] = *(const bf16x8*)((const char*)&SH[0][0] +
                ((ra * 128 + ks * 64 + c16 * 16) ^ ((ra & 7) << 4)));
        const int rbn = wc * 64 + r * 16 + r16;
        bfv[r] = *(const bf16x8*)((const char*)&SH[1][0] +
                ((rbn * 128 + ks * 64 + c16 * 16) ^ ((rbn & 7) << 4)));
      }
#pragma unroll
      for (int r = 0; r < 4; ++r)
#pragma unroll
        for (int c = 0; c < 4; ++c)
          acc[r][c] = __builtin_amdgcn_mfma_f32_16x16x32_bf16(
              af[r], bfv[c], acc[r][c], 0, 0, 0);
    }
    __syncthreads();
    if (kt + 1 < nk) stage(kt + 1);
    __syncthreads();
  }

  if (n0 < 2048) {
    // q/k scatter: 16 lanes write 32B contiguous (sector-efficient)
    const float qs = (n0 < 1024) ? 0.18033688f : 1.0f;  // 0.125*log2e for q
    u16* dst0 = (n0 < 1024) ? qo : ko;
#pragma unroll
    for (int r = 0; r < 4; ++r)
#pragma unroll
      for (int c = 0; c < 4; ++c)
#pragma unroll
        for (int b = 0; b < 4; ++b) {
          const int row = m0 + wr * 64 + r * 16 + 4 * c16 + b;
          const int col = n0 + wc * 64 + c * 16 + r16;
          const int hh = (col & 1023) >> 6, hd = col & 63;
          const int bi = row >> 11, s = row & 2047;
          dst0[((size_t)(bi * 16 + hh) * 2048 + s) * 64 + hd] =
              f2bf(acc[r][c][b] * qs);
        }
  } else {
    // V block: transpose 128x128 through LDS (free after K-loop), then
    // store tiled V^T: v2[bh][s/64][hd][64] — 16B contiguous chunks.
#pragma unroll
    for (int r = 0; r < 4; ++r)
#pragma unroll
      for (int c = 0; c < 4; ++c)
#pragma unroll
        for (int b = 0; b < 4; b += 2) {
          const int row_l = wr * 64 + r * 16 + 4 * c16 + b;
          const int col_l = wc * 64 + c * 16 + r16;
          const u32 val = (u32)f2bf(acc[r][c][b]) |
                          ((u32)f2bf(acc[r][c][b + 1]) << 16);
          *(u32*)((char*)&SH[0][0] +
                  ((col_l * 256 + (row_l >> 1) * 4) ^ ((col_l & 7) << 4))) = val;
        }
    __syncthreads();
    const int col_l = tid >> 1, half = tid & 1;
    const int hh = (n0 - 2048 + col_l) >> 6, hd = (n0 - 2048 + col_l) & 63;
    const int bi = m0 >> 11;
    const int tile = ((m0 & 2047) >> 6) + half;  // 64-key tile index
    u16* dst = vo + (size_t)(bi * 16 + hh) * 131072 + tile * 4096 + hd * 64;
#pragma unroll
    for (int j = 0; j < 8; ++j) {
      const uint4 v4 = *(const uint4*)((const char*)&SH[0][0] +
          (col_l * 256 + ((half * 128 + j * 16) ^ ((col_l & 7) << 4))));
      *(uint4*)(dst + j * 8) = v4;
    }
  }
}

// Output-projection GEMM (fp32 out): 64x128 tile, 2 waves, LDS 24KB.
// Grid (8,64) = 512 blocks = 2/CU co-resident; ~11us, near floor.
__global__ __launch_bounds__(128, 3) void gemm_proj(
    const u16* __restrict__ A, const u16* __restrict__ Bm, int K, int N,
    float* __restrict__ fo) {
  __shared__ __align__(16) u16 Asm[64 * 64];    // 8KB
  __shared__ __align__(16) u16 Bsm[128 * 64];   // 16KB
  const int tid = threadIdx.x;
  const int lane = tid & 63, w = tid >> 6;      // 2 waves
  const int hfl = blockIdx.y * gridDim.x + blockIdx.x;
  const int qq = (gridDim.x * gridDim.y) >> 3;
  const int wid = (hfl & 7) * qq + (hfl >> 3);
  const int m0 = (wid % gridDim.y) * 64;
  const int n0 = (wid / gridDim.y) * 128;
  const int c16 = lane >> 4, r16 = lane & 15;

  const f32x4 zero4 = {0.f, 0.f, 0.f, 0.f};
  f32x4 acc[4][4];
#pragma unroll
  for (int r = 0; r < 4; ++r)
#pragma unroll
    for (int c = 0; c < 4; ++c) acc[r][c] = zero4;

  const int nk = K >> 6;

  auto stage = [&](int kt) {
#pragma unroll
    for (int i = 0; i < 4; ++i) {
      const int chunk = w * 4 + i;              // 8 chunks of 1KB (A)
      const int lb = chunk * 1024 + lane * 16;
      const int row = lb >> 7;
      const int rb = (lb & 127) ^ ((row & 7) << 4);
      gload_lds16(A + (size_t)(m0 + row) * K + kt * 64 + (rb >> 1),
                  (char*)&Asm[0] + chunk * 1024);
    }
#pragma unroll
    for (int i = 0; i < 8; ++i) {
      const int chunk = w * 8 + i;              // 16 chunks of 1KB (B)
      const int lb = chunk * 1024 + lane * 16;
      const int row = lb >> 7;
      const int rb = (lb & 127) ^ ((row & 7) << 4);
      gload_lds16(Bm + (size_t)(n0 + row) * K + kt * 64 + (rb >> 1),
                  (char*)&Bsm[0] + chunk * 1024);
    }
  };

  stage(0);
  __syncthreads();
  for (int kt = 0; kt < nk; ++kt) {
#pragma unroll
    for (int ks = 0; ks < 2; ++ks) {
      bf16x8 af[4], bfv[4];
#pragma unroll
      for (int r = 0; r < 4; ++r) {
        const int ra = r * 16 + r16;            // rows 0..63 (full M-tile)
        af[r] = *(const bf16x8*)((const char*)&Asm[0] +
                ((ra * 128 + ks * 64 + c16 * 16) ^ ((ra & 7) << 4)));
        const int rbn = w * 64 + r * 16 + r16;  // own 64-col half of B
        bfv[r] = *(const bf16x8*)((const char*)&Bsm[0] +
                ((rbn * 128 + ks * 64 + c16 * 16) ^ ((rbn & 7) << 4)));
      }
#pragma unroll
      for (int r = 0; r < 4; ++r)
#pragma unroll
        for (int c = 0; c < 4; ++c)
          acc[r][c] = __builtin_amdgcn_mfma_f32_16x16x32_bf16(
              af[r], bfv[c], acc[r][c], 0, 0, 0);
    }
    __syncthreads();
    if (kt + 1 < nk) stage(kt + 1);
    __syncthreads();
  }

#pragma unroll
  for (int r = 0; r < 4; ++r)
#pragma unroll
    for (int c = 0; c < 4; ++c)
#pragma unroll
      for (int b = 0; b < 4; ++b) {
        const int row = m0 + r * 16 + 4 * c16 + b;
        const int col = n0 + w * 64 + c * 16 + r16;
        fo[(size_t)row * N + col] = acc[r][c][b];
      }
}

// Flash attention, ALiBi + causal. Round-8: round-7 structure (K in LDS
// 16.4KB dbuf, V direct from TILED V^T) with launch_bounds back to (256,5).
// Round-7's (256,8) forced a 32-VGPR allocation -> massive scratch spill
// (FETCH 217MB / WRITE 250MB, 186us). Round-6 evidence: this body compiles
// at 48 VGPR under (256,5) — no spill, and 48<=64 still allows 8 blocks/CU
// at runtime (LDS cap 9, thread cap 8).
__global__ __launch_bounds__(256, 5) void attn_part(const u16* __restrict__ qb,
                                                    const u16* __restrict__ kb,
                                                    const u16* __restrict__ vtb,
                                                    u16* __restrict__ ob,
                                                    u16* __restrict__ Op,
                                                    float* __restrict__ ml) {
  __shared__ __align__(16) u16 Kl[2][64 * 64];  // [key][hd], swizzled, 16KB

  const int tid = threadIdx.x;
  const int lane = tid & 63, w = tid >> 6;
  const int lo = lane & 15, hi = lane >> 4;
  const int yb = blockIdx.y;
  const int h = 15 - (yb >> 1), bi = yb & 1;   // LPT: heavy heads first
  const int bh = bi * 16 + h;
  const int y = blockIdx.x;                     // work item; XCD = x%8

  int qt, t0, t1, slot = 0;
  bool part;
  if (y < 16) {           // chunk1 of qt = 31-y  (len 9..16, has diag)
    qt = 31 - y;
    const int T = qt + 1;
    t0 = T >> 1; t1 = T; part = true;
    slot = bh * 32 + (qt - 16) * 2 + 1;
  } else if (y < 32) {    // chunk0 of qt = 47-y  (len 8..16)
    qt = 47 - y;
    const int T = qt + 1;
    t0 = 0; t1 = T >> 1; part = true;
    slot = bh * 32 + (qt - 16) * 2;
  } else {                // direct qt = 47-y     (len 1..16)
    qt = 47 - y;
    t0 = 0; t1 = qt + 1; part = false;
  }

  const int q0 = qt * 64;
  const float slope2 = exp2f(-0.5f * (float)(h + 1)) * 1.44269504089f;
  const float s64 = slope2 * 64.f;

  const int Dt = min(32, (int)ceilf(34.f / s64));
  t1 = min(t1, Dt);

  if (part && t0 >= t1) {
#pragma unroll
    for (int g = 0; g < 4; ++g)
#pragma unroll
      for (int r = 0; r < 4; ++r) {
        const int sl = w * 16 + 4 * hi + r;
        Op[(size_t)slot * 4096 + sl * 64 + g * 16 + lo] = 0;
      }
    if (hi == 0) ml[slot * 64 + w * 16 + lo] = 0.f;
    return;
  }

  const u16* __restrict__ Q = qb + (size_t)bh * 131072;
  const u16* __restrict__ Kp = kb + (size_t)bh * 131072;
  const u16* __restrict__ Vp = vtb + (size_t)bh * 131072;

  auto stageK = [&](int t, int buf) {
#pragma unroll
    for (int i = 0; i < 2; ++i) {
      const int chunk = w * 2 + i;
      const int lb = chunk * 1024 + lane * 16;
      const int row = lb >> 7;
      const int rb = (lb & 127) ^ ((row & 7) << 4);
      gload_lds16(Kp + (size_t)(t * 64 + row) * 64 + (rb >> 1),
                  (char*)&Kl[buf][0] + chunk * 1024);
    }
  };

  bf16x8 qf[2];
  {
    const u16* qsrc = Q + (size_t)(q0 + w * 16 + lo) * 64 + hi * 8;
    qf[0] = *(const bf16x8*)qsrc;
    qf[1] = *(const bf16x8*)(qsrc + 32);
  }

  const f32x4 zero4 = {0.f, 0.f, 0.f, 0.f};
  f32x4 oacc[4];
#pragma unroll
  for (int g = 0; g < 4; ++g) oacc[g] = zero4;
  float lsum = 0.f;

  float KC[4][4];
#pragma unroll
  for (int g = 0; g < 4; ++g)
#pragma unroll
    for (int r = 0; r < 4; ++r)
      KC[g][r] = slope2 * (float)(16 * g + 4 * hi + r);
  float ctv = 0.f;

  stageK(t0, 0);
  __syncthreads();

  for (int t = t0; t < t1; ++t) {
    const int cur = (t - t0) & 1, nxt = cur ^ 1;
    if (t + 1 < t1) stageK(t + 1, nxt);

    // V fragments for tile t from the tiled V^T (4KB contiguous tile;
    // L2/L1-resident; latency hidden under QK^T + softmax).
    bf16x8 vf[4][2];
#pragma unroll
    for (int g = 0; g < 4; ++g)
#pragma unroll
      for (int u = 0; u < 2; ++u)
        vf[g][u] = *(const bf16x8*)(Vp + (size_t)t * 4096 +
                                    (g * 16 + lo) * 64 + u * 32 + hi * 8);

    f32x4 st[4];
#pragma unroll
    for (int g = 0; g < 4; ++g) {
#pragma unroll
      for (int r = 0; r < 4; ++r) st[g][r] = ctv - KC[g][r];
#pragma unroll
      for (int ks = 0; ks < 2; ++ks) {
        const int krow = g * 16 + lo;
        const bf16x8 kf = *(const bf16x8*)((const char*)&Kl[cur][0] +
            ((krow * 128 + ks * 64 + hi * 16) ^ ((krow & 7) << 4)));
        st[g] = __builtin_amdgcn_mfma_f32_16x16x32_bf16(kf, qf[ks], st[g], 0, 0, 0);
      }
    }

    if (t == qt) {
#pragma unroll
      for (int g = 0; g < 4; ++g)
#pragma unroll
        for (int r = 0; r < 4; ++r)
          if (g * 16 + 4 * hi + r > w * 16 + lo) st[g][r] = -1e30f;
    }
    float p[4][4];
    float rs = 0.f;
#pragma unroll
    for (int g = 0; g < 4; ++g)
#pragma unroll
      for (int r = 0; r < 4; ++r) {
        p[g][r] = exp2f(st[g][r]);
        rs += p[g][r];
      }
    lsum += rs;

    u32 pk[4][2];
#pragma unroll
    for (int g = 0; g < 4; ++g)
#pragma unroll
      for (int c = 0; c < 2; ++c)
        pk[g][c] = __builtin_amdgcn_perm(
            __builtin_bit_cast(u32, p[g][2 * c + 1]),
            __builtin_bit_cast(u32, p[g][2 * c]), 0x07060302u);

    // P-repack via permlane swaps (round-3 proven lane-exact).
    bf16x8 pA[2];
#pragma unroll
    for (int u = 0; u < 2; ++u) {
      u32 x0 = pk[2 * u][0], x1 = pk[2 * u][1];
      u32 y0 = pk[2 * u + 1][0], y1 = pk[2 * u + 1][1];
      asm("v_permlane32_swap_b32 %0, %1" : "+v"(x0), "+v"(y0));
      asm("v_permlane32_swap_b32 %0, %1" : "+v"(x1), "+v"(y1));
      asm("v_permlane16_swap_b32 %0, %1" : "+v"(x0), "+v"(y0));
      asm("v_permlane16_swap_b32 %0, %1" : "+v"(x1), "+v"(y1));
      u32x4 wv;
      wv.x = x0;
      wv.y = x1;
      wv.z = y0;
      wv.w = y1;
      pA[u] = __builtin_bit_cast(bf16x8, wv);
    }

#pragma unroll
    for (int g = 0; g < 4; ++g) {
#pragma unroll
      for (int u = 0; u < 2; ++u) {
        oacc[g] = __builtin_amdgcn_mfma_f32_16x16x32_bf16(pA[u], vf[g][u],
                                                          oacc[g], 0, 0, 0);
      }
    }

    ctv -= s64;
    __syncthreads();
  }

  lsum += __shfl_xor(lsum, 16, 64);
  lsum += __shfl_xor(lsum, 32, 64);
  const float inv = 1.f / lsum;
  float iv[4];
#pragma unroll
  for (int r = 0; r < 4; ++r) iv[r] = __shfl(inv, 4 * hi + r, 64);

  if (!part) {
#pragma unroll
    for (int g = 0; g < 4; ++g)
#pragma unroll
      for (int r = 0; r < 4; ++r) {
        const int s = q0 + w * 16 + 4 * hi + r;
        const int hd = g * 16 + lo;
        ob[(((size_t)bi * 2048 + s) * 16 + h) * 64 + hd] =
            f2bf(oacc[g][r] * iv[r]);
      }
  } else {
#pragma unroll
    for (int g = 0; g < 4; ++g)
#pragma unroll
      for (int r = 0; r < 4; ++r) {
        const int sl = w * 16 + 4 * hi + r;
        Op[(size_t)slot * 4096 + sl * 64 + g * 16 + lo] =
            f2bf(oacc[g][r] * iv[r]);
      }
    if (hi == 0) ml[slot * 64 + w * 16 + lo] = lsum;
  }
}

// Merge the two chunk partials for q-tiles 16..31 (analytic chunk weights:
// w0 = l0, w1 = l1 * exp2(-slope2*64*t0)). Pruned chunk1: l1 = 0 -> 0.
__global__ __launch_bounds__(256) void attn_comb(const u16* __restrict__ Op,
                                                 const float* __restrict__ ml,
                                                 u16* __restrict__ ob) {
  const int bh = blockIdx.x, q16 = blockIdx.y;
  const int h = bh & 15, bi = bh >> 4;
  const int qt = 16 + q16;
  const int t0c = (qt + 1) >> 1;
  const float slope2 = exp2f(-0.5f * (float)(h + 1)) * 1.44269504089f;
  const float e1 = exp2f(-slope2 * 64.f * (float)t0c);
  const int slot0 = bh * 32 + q16 * 2;
  const int row = threadIdx.x >> 2, c0 = (threadIdx.x & 3) * 16;
  const float l0 = ml[slot0 * 64 + row];
  const float l1 = ml[(slot0 + 1) * 64 + row];
  const float w0 = l0, w1 = l1 * e1;
  const float inv = 1.f / (w0 + w1);
  const float a0 = w0 * inv, a1 = w1 * inv;
  const u16* p0 = Op + (size_t)slot0 * 4096 + row * 64 + c0;
  const u16* p1 = p0 + 4096;
  u32 A0[8], A1[8];
  *(uint4*)&A0[0] = *(const uint4*)p0;
  *(uint4*)&A0[4] = *(const uint4*)(p0 + 8);
  *(uint4*)&A1[0] = *(const uint4*)p1;
  *(uint4*)&A1[4] = *(const uint4*)(p1 + 8);
  const int s = qt * 64 + row;
  u32* dst = (u32*)(ob + (((size_t)bi * 2048 + s) * 16 + h) * 64 + c0);
#pragma unroll
  for (int j = 0; j < 8; ++j) {
    const float e0 = a0 * bf2f((u16)(A0[j] & 0xffffu)) +
                     a1 * bf2f((u16)(A1[j] & 0xffffu));
    const float ee1 = a0 * bf2f((u16)(A0[j] >> 16)) +
                      a1 * bf2f((u16)(A1[j] >> 16));
    dst[j] = (u32)f2bf(e0) | ((u32)f2bf(ee1) << 16);
  }
}

extern "C" void kernel_launch(void* const* d_in, const int* in_sizes, int n_in,
                              void* d_out, int out_size, void* d_ws, size_t ws_size,
                              hipStream_t stream) {
  const float* x = (const float*)d_in[0];     // (2,2048,1024)
  const float* Wqkv = (const float*)d_in[1];  // (3072,1024)
  const float* Wo = (const float*)d_in[2];    // (1024,1024)
  float* out = (float*)d_out;                 // (2,2048,1024) fp32

  // workspace layout (u16 elements)
  u16* xb  = (u16*)d_ws;        // x bf16          4194304  | reused: O partials
  u16* wqb = xb + 4194304;      // W_qkv bf16      3145728  | reused: l partials
  u16* wob = wqb + 3145728;     // W_o bf16        1048576
  u16* qbf = wob + 1048576;     // q (b,h,s,hd), pre-scaled  4194304
  u16* kbf = qbf + 4194304;     // k (b,h,s,hd)    4194304
  u16* vbf = kbf + 4194304;     // v^T tiled (b,h,s/64,hd,64)  4194304
  u16* abf = vbf + 4194304;     // attn out (b,s,h,hd) 4194304

  u16* Op = xb;                 // 1024 slots x 4096 u16 (normalized O, bf16)
  float* ml = (float*)wqb;      // 1024 slots x 64 f32 (l per row)

  cvt_all<<<8192, 256, 0, stream>>>(x, Wqkv, Wo, xb, wqb, wob);

  gemm_qkv<<<dim3(24, 32), 256, 0, stream>>>(xb, wqb, 1024, qbf, kbf, vbf);
  attn_part<<<dim3(48, 32), 256, 0, stream>>>(qbf, kbf, vbf, abf, Op, ml);
  attn_comb<<<dim3(32, 16), 256, 0, stream>>>(Op, ml, abf);
  // 64x128 tile, 512 blocks = 2/CU (fills the machine; W_o L2-resident)
  gemm_proj<<<dim3(8, 64), 128, 0, stream>>>(abf, wob, 1024, 1024, out);
}

// Round 9
// 107.894 us; speedup vs baseline: 2.3181x; 1.4963x over previous
//
#include <hip/hip_runtime.h>

typedef unsigned short u16;
typedef unsigned int u32;
typedef __attribute__((ext_vector_type(8))) __bf16 bf16x8;
typedef __attribute__((ext_vector_type(4))) float f32x4;
typedef __attribute__((ext_vector_type(4))) u32 u32x4;

// B=2, S=2048, DIM=1024, H=16, HD=64

static __device__ __forceinline__ u16 f2bf(float f) {
  unsigned u = __builtin_bit_cast(unsigned, f);
  u += 0x7FFFu + ((u >> 16) & 1u);
  return (u16)(u >> 16);
}
static __device__ __forceinline__ float bf2f(u16 v) {
  return __builtin_bit_cast(float, (u32)v << 16);
}

static __device__ __forceinline__ void gload_lds16(const void* g, void* l) {
  __builtin_amdgcn_global_load_lds(
      (const __attribute__((address_space(1))) unsigned int*)g,
      (__attribute__((address_space(3))) unsigned int*)l, 16, 0, 0);
}

// One kernel converts x, W_qkv, W_o (fp32 -> bf16). 2097152 float4 total.
__global__ __launch_bounds__(256) void cvt_all(const float* __restrict__ x,
                                               const float* __restrict__ wq,
                                               const float* __restrict__ wo,
                                               u16* __restrict__ xb,
                                               u16* __restrict__ wqb,
                                               u16* __restrict__ wob) {
  int i = blockIdx.x * 256 + threadIdx.x;
  const float* src;
  u16* dst;
  int off;
  if (i < 1048576) {
    src = x; dst = xb; off = i;
  } else if (i < 1048576 + 786432) {
    src = wq; dst = wqb; off = i - 1048576;
  } else {
    src = wo; dst = wob; off = i - 1835008;
  }
  float4 f = ((const float4*)src)[off];
  uint2 o;
  o.x = (unsigned)f2bf(f.x) | ((unsigned)f2bf(f.y) << 16);
  o.y = (unsigned)f2bf(f.z) | ((unsigned)f2bf(f.w) << 16);
  ((uint2*)dst)[off] = o;
}

// QKV GEMM. C[m,n] = sum_k A[m,k]*B[n,k]. 128x128 tile, BK=64, single 32KB
// buffer pair, two __syncthreads per K-step (best structure for this shape).
// q (pre-scaled by 0.125*log2e) / k scattered to (b,h,s,hd); V blocks
// (n0>=2048) transposed through LDS and stored as TILED V^T:
// v2[bh][tile=s/64][hd][64 keys] — 4KB contiguous per 64-key tile.
__global__ __launch_bounds__(256, 2) void gemm_qkv(
    const u16* __restrict__ A, const u16* __restrict__ Bm, int K,
    u16* __restrict__ qo, u16* __restrict__ ko, u16* __restrict__ vo) {
  __shared__ __align__(16) u16 SH[2][128 * 64];  // A-tile, B-tile; reused for V^T
  const int tid = threadIdx.x;
  const int lane = tid & 63, w = tid >> 6;
  const int wr = w >> 1, wc = w & 1;
  // T1: XCD-aware bijective swizzle (nwg % 8 == 0).
  const int hfl = blockIdx.y * gridDim.x + blockIdx.x;
  const int qq = (gridDim.x * gridDim.y) >> 3;
  const int wid = (hfl & 7) * qq + (hfl >> 3);
  const int m0 = (wid % gridDim.y) * 128;
  const int n0 = (wid / gridDim.y) * 128;
  const int c16 = lane >> 4, r16 = lane & 15;

  const f32x4 zero4 = {0.f, 0.f, 0.f, 0.f};
  f32x4 acc[4][4];
#pragma unroll
  for (int r = 0; r < 4; ++r)
#pragma unroll
    for (int c = 0; c < 4; ++c) acc[r][c] = zero4;

  const int nk = K >> 6;

  // LDS tile: [128 rows][64 cols] bf16, byte ^= ((row&7)<<4) swizzle.
  // global_load_lds writes linearly -> pre-swizzled SOURCE (rule #21).
  auto stage = [&](int kt) {
#pragma unroll
    for (int i = 0; i < 4; ++i) {
      const int chunk = w * 4 + i;
      const int lb = chunk * 1024 + lane * 16;
      const int row = lb >> 7;
      const int rb = (lb & 127) ^ ((row & 7) << 4);
      gload_lds16(A + (size_t)(m0 + row) * K + kt * 64 + (rb >> 1),
                  (char*)&SH[0][0] + chunk * 1024);
      gload_lds16(Bm + (size_t)(n0 + row) * K + kt * 64 + (rb >> 1),
                  (char*)&SH[1][0] + chunk * 1024);
    }
  };

  stage(0);
  __syncthreads();
  for (int kt = 0; kt < nk; ++kt) {
#pragma unroll
    for (int ks = 0; ks < 2; ++ks) {
      bf16x8 af[4], bfv[4];
#pragma unroll
      for (int r = 0; r < 4; ++r) {
        const int ra = wr * 64 + r * 16 + r16;
        af[r] = *(const bf16x8*)((const char*)&SH[0][0] +
                ((ra * 128 + ks * 64 + c16 * 16) ^ ((ra & 7) << 4)));
        const int rbn = wc * 64 + r * 16 + r16;
        bfv[r] = *(const bf16x8*)((const char*)&SH[1][0] +
                ((rbn * 128 + ks * 64 + c16 * 16) ^ ((rbn & 7) << 4)));
      }
#pragma unroll
      for (int r = 0; r < 4; ++r)
#pragma unroll
        for (int c = 0; c < 4; ++c)
          acc[r][c] = __builtin_amdgcn_mfma_f32_16x16x32_bf16(
              af[r], bfv[c], acc[r][c], 0, 0, 0);
    }
    __syncthreads();
    if (kt + 1 < nk) stage(kt + 1);
    __syncthreads();
  }

  if (n0 < 2048) {
    // q/k scatter: 16 lanes write 32B contiguous (sector-efficient)
    const float qs = (n0 < 1024) ? 0.18033688f : 1.0f;  // 0.125*log2e for q
    u16* dst0 = (n0 < 1024) ? qo : ko;
#pragma unroll
    for (int r = 0; r < 4; ++r)
#pragma unroll
      for (int c = 0; c < 4; ++c)
#pragma unroll
        for (int b = 0; b < 4; ++b) {
          const int row = m0 + wr * 64 + r * 16 + 4 * c16 + b;
          const int col = n0 + wc * 64 + c * 16 + r16;
          const int hh = (col & 1023) >> 6, hd = col & 63;
          const int bi = row >> 11, s = row & 2047;
          dst0[((size_t)(bi * 16 + hh) * 2048 + s) * 64 + hd] =
              f2bf(acc[r][c][b] * qs);
        }
  } else {
    // V block: transpose 128x128 through LDS (free after K-loop), then
    // store tiled V^T: v2[bh][s/64][hd][64] — 16B contiguous chunks.
#pragma unroll
    for (int r = 0; r < 4; ++r)
#pragma unroll
      for (int c = 0; c < 4; ++c)
#pragma unroll
        for (int b = 0; b < 4; b += 2) {
          const int row_l = wr * 64 + r * 16 + 4 * c16 + b;
          const int col_l = wc * 64 + c * 16 + r16;
          const u32 val = (u32)f2bf(acc[r][c][b]) |
                          ((u32)f2bf(acc[r][c][b + 1]) << 16);
          *(u32*)((char*)&SH[0][0] +
                  ((col_l * 256 + (row_l >> 1) * 4) ^ ((col_l & 7) << 4))) = val;
        }
    __syncthreads();
    const int col_l = tid >> 1, half = tid & 1;
    const int hh = (n0 - 2048 + col_l) >> 6, hd = (n0 - 2048 + col_l) & 63;
    const int bi = m0 >> 11;
    const int tile = ((m0 & 2047) >> 6) + half;  // 64-key tile index
    u16* dst = vo + (size_t)(bi * 16 + hh) * 131072 + tile * 4096 + hd * 64;
#pragma unroll
    for (int j = 0; j < 8; ++j) {
      const uint4 v4 = *(const uint4*)((const char*)&SH[0][0] +
          (col_l * 256 + ((half * 128 + j * 16) ^ ((col_l & 7) << 4))));
      *(uint4*)(dst + j * 8) = v4;
    }
  }
}

// Output-projection GEMM (fp32 out): 64x128 tile, 2 waves, LDS 24KB.
// Grid (8,64) = 512 blocks = 2/CU co-resident; ~11us, near floor.
__global__ __launch_bounds__(128, 3) void gemm_proj(
    const u16* __restrict__ A, const u16* __restrict__ Bm, int K, int N,
    float* __restrict__ fo) {
  __shared__ __align__(16) u16 Asm[64 * 64];    // 8KB
  __shared__ __align__(16) u16 Bsm[128 * 64];   // 16KB
  const int tid = threadIdx.x;
  const int lane = tid & 63, w = tid >> 6;      // 2 waves
  const int hfl = blockIdx.y * gridDim.x + blockIdx.x;
  const int qq = (gridDim.x * gridDim.y) >> 3;
  const int wid = (hfl & 7) * qq + (hfl >> 3);
  const int m0 = (wid % gridDim.y) * 64;
  const int n0 = (wid / gridDim.y) * 128;
  const int c16 = lane >> 4, r16 = lane & 15;

  const f32x4 zero4 = {0.f, 0.f, 0.f, 0.f};
  f32x4 acc[4][4];
#pragma unroll
  for (int r = 0; r < 4; ++r)
#pragma unroll
    for (int c = 0; c < 4; ++c) acc[r][c] = zero4;

  const int nk = K >> 6;

  auto stage = [&](int kt) {
#pragma unroll
    for (int i = 0; i < 4; ++i) {
      const int chunk = w * 4 + i;              // 8 chunks of 1KB (A)
      const int lb = chunk * 1024 + lane * 16;
      const int row = lb >> 7;
      const int rb = (lb & 127) ^ ((row & 7) << 4);
      gload_lds16(A + (size_t)(m0 + row) * K + kt * 64 + (rb >> 1),
                  (char*)&Asm[0] + chunk * 1024);
    }
#pragma unroll
    for (int i = 0; i < 8; ++i) {
      const int chunk = w * 8 + i;              // 16 chunks of 1KB (B)
      const int lb = chunk * 1024 + lane * 16;
      const int row = lb >> 7;
      const int rb = (lb & 127) ^ ((row & 7) << 4);
      gload_lds16(Bm + (size_t)(n0 + row) * K + kt * 64 + (rb >> 1),
                  (char*)&Bsm[0] + chunk * 1024);
    }
  };

  stage(0);
  __syncthreads();
  for (int kt = 0; kt < nk; ++kt) {
#pragma unroll
    for (int ks = 0; ks < 2; ++ks) {
      bf16x8 af[4], bfv[4];
#pragma unroll
      for (int r = 0; r < 4; ++r) {
        const int ra = r * 16 + r16;            // rows 0..63 (full M-tile)
        af[r] = *(const bf16x8*)((const char*)&Asm[0] +
                ((ra * 128 + ks * 64 + c16 * 16) ^ ((ra & 7) << 4)));
        const int rbn = w * 64 + r * 16 + r16;  // own 64-col half of B
        bfv[r] = *(const bf16x8*)((const char*)&Bsm[0] +
                ((rbn * 128 + ks * 64 + c16 * 16) ^ ((rbn & 7) << 4)));
      }
#pragma unroll
      for (int r = 0; r < 4; ++r)
#pragma unroll
        for (int c = 0; c < 4; ++c)
          acc[r][c] = __builtin_amdgcn_mfma_f32_16x16x32_bf16(
              af[r], bfv[c], acc[r][c], 0, 0, 0);
    }
    __syncthreads();
    if (kt + 1 < nk) stage(kt + 1);
    __syncthreads();
  }

#pragma unroll
  for (int r = 0; r < 4; ++r)
#pragma unroll
    for (int c = 0; c < 4; ++c)
#pragma unroll
      for (int b = 0; b < 4; ++b) {
        const int row = m0 + r * 16 + 4 * c16 + b;
        const int col = n0 + w * 64 + c * 16 + r16;
        fo[(size_t)row * N + col] = acc[r][c][b];
      }
}

// Flash attention, ALiBi + causal. Round-9: round-3 structure restored
// (K AND V double-buffered in LDS — round-8 falsified direct-V: FETCH 78MB,
// 100us, because each XCD's L2 faced the full 16MB K/V set), plus:
// (a) XCD<->head affinity: xcd = linear%8 selects a {heavy,light} head pair
//     (15-p, p) x both batches -> per-XCD K+V+Q working set ~3MB <= 4MB L2;
//     staging loads become L2 hits, shortening the barrier-drain critical
//     path. Bijective: 8 xcd x 4 bh x 48 work = 1536 blocks.
// (b) V staged from the TILED V^T (contiguous 8KB/tile source).
// Same per-block work and accumulation order -> bit-identical numerics.
__global__ __launch_bounds__(256, 5) void attn_part(const u16* __restrict__ qb,
                                                    const u16* __restrict__ kb,
                                                    const u16* __restrict__ vtb,
                                                    u16* __restrict__ ob,
                                                    u16* __restrict__ Op,
                                                    float* __restrict__ ml) {
  __shared__ __align__(16) u16 Kl[2][64 * 64];  // [key][hd], swizzled
  __shared__ __align__(16) u16 Vt[2][64 * 64];  // [hd][key], swizzled

  const int tid = threadIdx.x;
  const int lane = tid & 63, w = tid >> 6;
  const int lo = lane & 15, hi = lane >> 4;
  // XCD-affinity decode (xcd = linear block id % 8 on MI355X):
  const int linear = blockIdx.y * 48 + blockIdx.x;
  const int xcd = linear & 7;
  const int jj = (linear >> 3) & 3;
  const int y = linear >> 5;                    // work item 0..47
  const int h = (jj & 2) ? xcd : (15 - xcd);    // head pair {15-p, p}
  const int bi = jj & 1;
  const int bh = bi * 16 + h;

  int qt, t0, t1, slot = 0;
  bool part;
  if (y < 16) {           // chunk1 of qt = 31-y  (len 9..16, has diag)
    qt = 31 - y;
    const int T = qt + 1;
    t0 = T >> 1; t1 = T; part = true;
    slot = bh * 32 + (qt - 16) * 2 + 1;
  } else if (y < 32) {    // chunk0 of qt = 47-y  (len 8..16)
    qt = 47 - y;
    const int T = qt + 1;
    t0 = 0; t1 = T >> 1; part = true;
    slot = bh * 32 + (qt - 16) * 2;
  } else {                // direct qt = 47-y     (len 1..16)
    qt = 47 - y;
    t0 = 0; t1 = qt + 1; part = false;
  }

  const int q0 = qt * 64;
  const float slope2 = exp2f(-0.5f * (float)(h + 1)) * 1.44269504089f;
  const float s64 = slope2 * 64.f;

  const int Dt = min(32, (int)ceilf(34.f / s64));
  t1 = min(t1, Dt);

  if (part && t0 >= t1) {
#pragma unroll
    for (int g = 0; g < 4; ++g)
#pragma unroll
      for (int r = 0; r < 4; ++r) {
        const int sl = w * 16 + 4 * hi + r;
        Op[(size_t)slot * 4096 + sl * 64 + g * 16 + lo] = 0;
      }
    if (hi == 0) ml[slot * 64 + w * 16 + lo] = 0.f;
    return;
  }

  const u16* __restrict__ Q = qb + (size_t)bh * 131072;
  const u16* __restrict__ Kp = kb + (size_t)bh * 131072;
  const u16* __restrict__ Vp = vtb + (size_t)bh * 131072;

  auto stageK = [&](int t, int buf) {
#pragma unroll
    for (int i = 0; i < 2; ++i) {
      const int chunk = w * 2 + i;
      const int lb = chunk * 1024 + lane * 16;
      const int row = lb >> 7;
      const int rb = (lb & 127) ^ ((row & 7) << 4);
      gload_lds16(Kp + (size_t)(t * 64 + row) * 64 + (rb >> 1),
                  (char*)&Kl[buf][0] + chunk * 1024);
    }
  };
  // V from tiled V^T: tile t is 8KB contiguous [hd][128B keys].
  auto stageV = [&](int t, int buf) {
#pragma unroll
    for (int i = 0; i < 2; ++i) {
      const int chunk = w * 2 + i;
      const int lb = chunk * 1024 + lane * 16;
      const int row = lb >> 7;  // = hd
      const int rb = (lb & 127) ^ ((row & 7) << 4);
      gload_lds16(Vp + (size_t)t * 4096 + row * 64 + (rb >> 1),
                  (char*)&Vt[buf][0] + chunk * 1024);
    }
  };

  bf16x8 qf[2];
  {
    const u16* qsrc = Q + (size_t)(q0 + w * 16 + lo) * 64 + hi * 8;
    qf[0] = *(const bf16x8*)qsrc;
    qf[1] = *(const bf16x8*)(qsrc + 32);
  }

  const f32x4 zero4 = {0.f, 0.f, 0.f, 0.f};
  f32x4 oacc[4];
#pragma unroll
  for (int g = 0; g < 4; ++g) oacc[g] = zero4;
  float lsum = 0.f;

  float KC[4][4];
#pragma unroll
  for (int g = 0; g < 4; ++g)
#pragma unroll
    for (int r = 0; r < 4; ++r)
      KC[g][r] = slope2 * (float)(16 * g + 4 * hi + r);
  float ctv = 0.f;

  stageK(t0, 0);
  stageV(t0, 0);
  __syncthreads();

  for (int t = t0; t < t1; ++t) {
    const int cur = (t - t0) & 1, nxt = cur ^ 1;
    if (t + 1 < t1) {
      stageK(t + 1, nxt);
      stageV(t + 1, nxt);
    }

    f32x4 st[4];
#pragma unroll
    for (int g = 0; g < 4; ++g) {
#pragma unroll
      for (int r = 0; r < 4; ++r) st[g][r] = ctv - KC[g][r];
#pragma unroll
      for (int ks = 0; ks < 2; ++ks) {
        const int krow = g * 16 + lo;
        const bf16x8 kf = *(const bf16x8*)((const char*)&Kl[cur][0] +
            ((krow * 128 + ks * 64 + hi * 16) ^ ((krow & 7) << 4)));
        st[g] = __builtin_amdgcn_mfma_f32_16x16x32_bf16(kf, qf[ks], st[g], 0, 0, 0);
      }
    }

    if (t == qt) {
#pragma unroll
      for (int g = 0; g < 4; ++g)
#pragma unroll
        for (int r = 0; r < 4; ++r)
          if (g * 16 + 4 * hi + r > w * 16 + lo) st[g][r] = -1e30f;
    }
    float p[4][4];
    float rs = 0.f;
#pragma unroll
    for (int g = 0; g < 4; ++g)
#pragma unroll
      for (int r = 0; r < 4; ++r) {
        p[g][r] = exp2f(st[g][r]);
        rs += p[g][r];
      }
    lsum += rs;

    u32 pk[4][2];
#pragma unroll
    for (int g = 0; g < 4; ++g)
#pragma unroll
      for (int c = 0; c < 2; ++c)
        pk[g][c] = __builtin_amdgcn_perm(
            __builtin_bit_cast(u32, p[g][2 * c + 1]),
            __builtin_bit_cast(u32, p[g][2 * c]), 0x07060302u);

    // P-repack via permlane swaps (round-3 proven lane-exact).
    bf16x8 pA[2];
#pragma unroll
    for (int u = 0; u < 2; ++u) {
      u32 x0 = pk[2 * u][0], x1 = pk[2 * u][1];
      u32 y0 = pk[2 * u + 1][0], y1 = pk[2 * u + 1][1];
      asm("v_permlane32_swap_b32 %0, %1" : "+v"(x0), "+v"(y0));
      asm("v_permlane32_swap_b32 %0, %1" : "+v"(x1), "+v"(y1));
      asm("v_permlane16_swap_b32 %0, %1" : "+v"(x0), "+v"(y0));
      asm("v_permlane16_swap_b32 %0, %1" : "+v"(x1), "+v"(y1));
      u32x4 wv;
      wv.x = x0;
      wv.y = x1;
      wv.z = y0;
      wv.w = y1;
      pA[u] = __builtin_bit_cast(bf16x8, wv);
    }

#pragma unroll
    for (int g = 0; g < 4; ++g) {
#pragma unroll
      for (int u = 0; u < 2; ++u) {
        const int vrow = g * 16 + lo;
        const bf16x8 vf = *(const bf16x8*)((const char*)&Vt[cur][0] +
            ((vrow * 128 + u * 64 + hi * 16) ^ ((vrow & 7) << 4)));
        oacc[g] = __builtin_amdgcn_mfma_f32_16x16x32_bf16(pA[u], vf, oacc[g], 0, 0, 0);
      }
    }

    ctv -= s64;
    __syncthreads();
  }

  lsum += __shfl_xor(lsum, 16, 64);
  lsum += __shfl_xor(lsum, 32, 64);
  const float inv = 1.f / lsum;
  float iv[4];
#pragma unroll
  for (int r = 0; r < 4; ++r) iv[r] = __shfl(inv, 4 * hi + r, 64);

  if (!part) {
#pragma unroll
    for (int g = 0; g < 4; ++g)
#pragma unroll
      for (int r = 0; r < 4; ++r) {
        const int s = q0 + w * 16 + 4 * hi + r;
        const int hd = g * 16 + lo;
        ob[(((size_t)bi * 2048 + s) * 16 + h) * 64 + hd] =
            f2bf(oacc[g][r] * iv[r]);
      }
  } else {
#pragma unroll
    for (int g = 0; g < 4; ++g)
#pragma unroll
      for (int r = 0; r < 4; ++r) {
        const int sl = w * 16 + 4 * hi + r;
        Op[(size_t)slot * 4096 + sl * 64 + g * 16 + lo] =
            f2bf(oacc[g][r] * iv[r]);
      }
    if (hi == 0) ml[slot * 64 + w * 16 + lo] = lsum;
  }
}

// Merge the two chunk partials for q-tiles 16..31 (analytic chunk weights:
// w0 = l0, w1 = l1 * exp2(-slope2*64*t0)). Pruned chunk1: l1 = 0 -> 0.
__global__ __launch_bounds__(256) void attn_comb(const u16* __restrict__ Op,
                                                 const float* __restrict__ ml,
                                                 u16* __restrict__ ob) {
  const int bh = blockIdx.x, q16 = blockIdx.y;
  const int h = bh & 15, bi = bh >> 4;
  const int qt = 16 + q16;
  const int t0c = (qt + 1) >> 1;
  const float slope2 = exp2f(-0.5f * (float)(h + 1)) * 1.44269504089f;
  const float e1 = exp2f(-slope2 * 64.f * (float)t0c);
  const int slot0 = bh * 32 + q16 * 2;
  const int row = threadIdx.x >> 2, c0 = (threadIdx.x & 3) * 16;
  const float l0 = ml[slot0 * 64 + row];
  const float l1 = ml[(slot0 + 1) * 64 + row];
  const float w0 = l0, w1 = l1 * e1;
  const float inv = 1.f / (w0 + w1);
  const float a0 = w0 * inv, a1 = w1 * inv;
  const u16* p0 = Op + (size_t)slot0 * 4096 + row * 64 + c0;
  const u16* p1 = p0 + 4096;
  u32 A0[8], A1[8];
  *(uint4*)&A0[0] = *(const uint4*)p0;
  *(uint4*)&A0[4] = *(const uint4*)(p0 + 8);
  *(uint4*)&A1[0] = *(const uint4*)p1;
  *(uint4*)&A1[4] = *(const uint4*)(p1 + 8);
  const int s = qt * 64 + row;
  u32* dst = (u32*)(ob + (((size_t)bi * 2048 + s) * 16 + h) * 64 + c0);
#pragma unroll
  for (int j = 0; j < 8; ++j) {
    const float e0 = a0 * bf2f((u16)(A0[j] & 0xffffu)) +
                     a1 * bf2f((u16)(A1[j] & 0xffffu));
    const float ee1 = a0 * bf2f((u16)(A0[j] >> 16)) +
                      a1 * bf2f((u16)(A1[j] >> 16));
    dst[j] = (u32)f2bf(e0) | ((u32)f2bf(ee1) << 16);
  }
}

extern "C" void kernel_launch(void* const* d_in, const int* in_sizes, int n_in,
                              void* d_out, int out_size, void* d_ws, size_t ws_size,
                              hipStream_t stream) {
  const float* x = (const float*)d_in[0];     // (2,2048,1024)
  const float* Wqkv = (const float*)d_in[1];  // (3072,1024)
  const float* Wo = (const float*)d_in[2];    // (1024,1024)
  float* out = (float*)d_out;                 // (2,2048,1024) fp32

  // workspace layout (u16 elements)
  u16* xb  = (u16*)d_ws;        // x bf16          4194304  | reused: O partials
  u16* wqb = xb + 4194304;      // W_qkv bf16      3145728  | reused: l partials
  u16* wob = wqb + 3145728;     // W_o bf16        1048576
  u16* qbf = wob + 1048576;     // q (b,h,s,hd), pre-scaled  4194304
  u16* kbf = qbf + 4194304;     // k (b,h,s,hd)    4194304
  u16* vbf = kbf + 4194304;     // v^T tiled (b,h,s/64,hd,64)  4194304
  u16* abf = vbf + 4194304;     // attn out (b,s,h,hd) 4194304

  u16* Op = xb;                 // 1024 slots x 4096 u16 (normalized O, bf16)
  float* ml = (float*)wqb;      // 1024 slots x 64 f32 (l per row)

  cvt_all<<<8192, 256, 0, stream>>>(x, Wqkv, Wo, xb, wqb, wob);

  gemm_qkv<<<dim3(24, 32), 256, 0, stream>>>(xb, wqb, 1024, qbf, kbf, vbf);
  attn_part<<<dim3(48, 32), 256, 0, stream>>>(qbf, kbf, vbf, abf, Op, ml);
  attn_comb<<<dim3(32, 16), 256, 0, stream>>>(Op, ml, abf);
  // 64x128 tile, 512 blocks = 2/CU (fills the machine; W_o L2-resident)
  gemm_proj<<<dim3(8, 64), 128, 0, stream>>>(abf, wob, 1024, 1024, out);
}

// Round 10
// 99.725 us; speedup vs baseline: 2.5079x; 1.0819x over previous
//
#include <hip/hip_runtime.h>

typedef unsigned short u16;
typedef unsigned int u32;
typedef __attribute__((ext_vector_type(8))) __bf16 bf16x8;
typedef __attribute__((ext_vector_type(4))) float f32x4;
typedef __attribute__((ext_vector_type(4))) u32 u32x4;

// B=2, S=2048, DIM=1024, H=16, HD=64

static __device__ __forceinline__ u16 f2bf(float f) {
  unsigned u = __builtin_bit_cast(unsigned, f);
  u += 0x7FFFu + ((u >> 16) & 1u);
  return (u16)(u >> 16);
}
static __device__ __forceinline__ float bf2f(u16 v) {
  return __builtin_bit_cast(float, (u32)v << 16);
}

static __device__ __forceinline__ void gload_lds16(const void* g, void* l) {
  __builtin_amdgcn_global_load_lds(
      (const __attribute__((address_space(1))) unsigned int*)g,
      (__attribute__((address_space(3))) unsigned int*)l, 16, 0, 0);
}

// One kernel converts x, W_qkv, W_o (fp32 -> bf16). 2097152 float4 total.
__global__ __launch_bounds__(256) void cvt_all(const float* __restrict__ x,
                                               const float* __restrict__ wq,
                                               const float* __restrict__ wo,
                                               u16* __restrict__ xb,
                                               u16* __restrict__ wqb,
                                               u16* __restrict__ wob) {
  int i = blockIdx.x * 256 + threadIdx.x;
  const float* src;
  u16* dst;
  int off;
  if (i < 1048576) {
    src = x; dst = xb; off = i;
  } else if (i < 1048576 + 786432) {
    src = wq; dst = wqb; off = i - 1048576;
  } else {
    src = wo; dst = wob; off = i - 1835008;
  }
  float4 f = ((const float4*)src)[off];
  uint2 o;
  o.x = (unsigned)f2bf(f.x) | ((unsigned)f2bf(f.y) << 16);
  o.y = (unsigned)f2bf(f.z) | ((unsigned)f2bf(f.w) << 16);
  ((uint2*)dst)[off] = o;
}

// QKV GEMM. C[m,n] = sum_k A[m,k]*B[n,k]. 128x128 tile, BK=64, single 32KB
// buffer pair, two __syncthreads per K-step (best structure for this shape).
// q (pre-scaled by 0.125*log2e) / k scattered to (b,h,s,hd); V blocks
// (n0>=2048) transposed through LDS and stored as TILED V^T:
// v2[bh][tile=s/64][hd][64 keys] — 4KB contiguous per 64-key tile; fully
// contiguous stores here and contiguous stage-reads in attn (kills the
// 4KB-stride channel camping measured in rounds 6/8).
__global__ __launch_bounds__(256, 2) void gemm_qkv(
    const u16* __restrict__ A, const u16* __restrict__ Bm, int K,
    u16* __restrict__ qo, u16* __restrict__ ko, u16* __restrict__ vo) {
  __shared__ __align__(16) u16 SH[2][128 * 64];  // A-tile, B-tile; reused for V^T
  const int tid = threadIdx.x;
  const int lane = tid & 63, w = tid >> 6;
  const int wr = w >> 1, wc = w & 1;
  // T1: XCD-aware bijective swizzle (nwg % 8 == 0).
  const int hfl = blockIdx.y * gridDim.x + blockIdx.x;
  const int qq = (gridDim.x * gridDim.y) >> 3;
  const int wid = (hfl & 7) * qq + (hfl >> 3);
  const int m0 = (wid % gridDim.y) * 128;
  const int n0 = (wid / gridDim.y) * 128;
  const int c16 = lane >> 4, r16 = lane & 15;

  const f32x4 zero4 = {0.f, 0.f, 0.f, 0.f};
  f32x4 acc[4][4];
#pragma unroll
  for (int r = 0; r < 4; ++r)
#pragma unroll
    for (int c = 0; c < 4; ++c) acc[r][c] = zero4;

  const int nk = K >> 6;

  // LDS tile: [128 rows][64 cols] bf16, byte ^= ((row&7)<<4) swizzle.
  // global_load_lds writes linearly -> pre-swizzled SOURCE (rule #21).
  auto stage = [&](int kt) {
#pragma unroll
    for (int i = 0; i < 4; ++i) {
      const int chunk = w * 4 + i;
      const int lb = chunk * 1024 + lane * 16;
      const int row = lb >> 7;
      const int rb = (lb & 127) ^ ((row & 7) << 4);
      gload_lds16(A + (size_t)(m0 + row) * K + kt * 64 + (rb >> 1),
                  (char*)&SH[0][0] + chunk * 1024);
      gload_lds16(Bm + (size_t)(n0 + row) * K + kt * 64 + (rb >> 1),
                  (char*)&SH[1][0] + chunk * 1024);
    }
  };

  stage(0);
  __syncthreads();
  for (int kt = 0; kt < nk; ++kt) {
#pragma unroll
    for (int ks = 0; ks < 2; ++ks) {
      bf16x8 af[4], bfv[4];
#pragma unroll
      for (int r = 0; r < 4; ++r) {
        const int ra = wr * 64 + r * 16 + r16;
        af[r] = *(const bf16x8*)((const char*)&SH[0][0] +
                ((ra * 128 + ks * 64 + c16 * 16) ^ ((ra & 7) << 4)));
        const int rbn = wc * 64 + r * 16 + r16;
        bfv[r] = *(const bf16x8*)((const char*)&SH[1][0] +
                ((rbn * 128 + ks * 64 + c16 * 16) ^ ((rbn & 7) << 4)));
      }
#pragma unroll
      for (int r = 0; r < 4; ++r)
#pragma unroll
        for (int c = 0; c < 4; ++c)
          acc[r][c] = __builtin_amdgcn_mfma_f32_16x16x32_bf16(
              af[r], bfv[c], acc[r][c], 0, 0, 0);
    }
    __syncthreads();
    if (kt + 1 < nk) stage(kt + 1);
    __syncthreads();
  }

  if (n0 < 2048) {
    // q/k scatter: 16 lanes write 32B contiguous (sector-efficient)
    const float qs = (n0 < 1024) ? 0.18033688f : 1.0f;  // 0.125*log2e for q
    u16* dst0 = (n0 < 1024) ? qo : ko;
#pragma unroll
    for (int r = 0; r < 4; ++r)
#pragma unroll
      for (int c = 0; c < 4; ++c)
#pragma unroll
        for (int b = 0; b < 4; ++b) {
          const int row = m0 + wr * 64 + r * 16 + 4 * c16 + b;
          const int col = n0 + wc * 64 + c * 16 + r16;
          const int hh = (col & 1023) >> 6, hd = col & 63;
          const int bi = row >> 11, s = row & 2047;
          dst0[((size_t)(bi * 16 + hh) * 2048 + s) * 64 + hd] =
              f2bf(acc[r][c][b] * qs);
        }
  } else {
    // V block: transpose 128x128 through LDS (free after K-loop), then
    // store tiled V^T: v2[bh][s/64][hd][64] — 16B contiguous chunks.
#pragma unroll
    for (int r = 0; r < 4; ++r)
#pragma unroll
      for (int c = 0; c < 4; ++c)
#pragma unroll
        for (int b = 0; b < 4; b += 2) {
          const int row_l = wr * 64 + r * 16 + 4 * c16 + b;
          const int col_l = wc * 64 + c * 16 + r16;
          const u32 val = (u32)f2bf(acc[r][c][b]) |
                          ((u32)f2bf(acc[r][c][b + 1]) << 16);
          *(u32*)((char*)&SH[0][0] +
                  ((col_l * 256 + (row_l >> 1) * 4) ^ ((col_l & 7) << 4))) = val;
        }
    __syncthreads();
    const int col_l = tid >> 1, half = tid & 1;
    const int hh = (n0 - 2048 + col_l) >> 6, hd = (n0 - 2048 + col_l) & 63;
    const int bi = m0 >> 11;
    const int tile = ((m0 & 2047) >> 6) + half;  // 64-key tile index
    u16* dst = vo + (size_t)(bi * 16 + hh) * 131072 + tile * 4096 + hd * 64;
#pragma unroll
    for (int j = 0; j < 8; ++j) {
      const uint4 v4 = *(const uint4*)((const char*)&SH[0][0] +
          (col_l * 256 + ((half * 128 + j * 16) ^ ((col_l & 7) << 4))));
      *(uint4*)(dst + j * 8) = v4;
    }
  }
}

// Output-projection GEMM (fp32 out): 64x128 tile, 2 waves, LDS 24KB.
// Grid (8,64) = 512 blocks = 2/CU co-resident; ~11us, near floor.
__global__ __launch_bounds__(128, 3) void gemm_proj(
    const u16* __restrict__ A, const u16* __restrict__ Bm, int K, int N,
    float* __restrict__ fo) {
  __shared__ __align__(16) u16 Asm[64 * 64];    // 8KB
  __shared__ __align__(16) u16 Bsm[128 * 64];   // 16KB
  const int tid = threadIdx.x;
  const int lane = tid & 63, w = tid >> 6;      // 2 waves
  const int hfl = blockIdx.y * gridDim.x + blockIdx.x;
  const int qq = (gridDim.x * gridDim.y) >> 3;
  const int wid = (hfl & 7) * qq + (hfl >> 3);
  const int m0 = (wid % gridDim.y) * 64;
  const int n0 = (wid / gridDim.y) * 128;
  const int c16 = lane >> 4, r16 = lane & 15;

  const f32x4 zero4 = {0.f, 0.f, 0.f, 0.f};
  f32x4 acc[4][4];
#pragma unroll
  for (int r = 0; r < 4; ++r)
#pragma unroll
    for (int c = 0; c < 4; ++c) acc[r][c] = zero4;

  const int nk = K >> 6;

  auto stage = [&](int kt) {
#pragma unroll
    for (int i = 0; i < 4; ++i) {
      const int chunk = w * 4 + i;              // 8 chunks of 1KB (A)
      const int lb = chunk * 1024 + lane * 16;
      const int row = lb >> 7;
      const int rb = (lb & 127) ^ ((row & 7) << 4);
      gload_lds16(A + (size_t)(m0 + row) * K + kt * 64 + (rb >> 1),
                  (char*)&Asm[0] + chunk * 1024);
    }
#pragma unroll
    for (int i = 0; i < 8; ++i) {
      const int chunk = w * 8 + i;              // 16 chunks of 1KB (B)
      const int lb = chunk * 1024 + lane * 16;
      const int row = lb >> 7;
      const int rb = (lb & 127) ^ ((row & 7) << 4);
      gload_lds16(Bm + (size_t)(n0 + row) * K + kt * 64 + (rb >> 1),
                  (char*)&Bsm[0] + chunk * 1024);
    }
  };

  stage(0);
  __syncthreads();
  for (int kt = 0; kt < nk; ++kt) {
#pragma unroll
    for (int ks = 0; ks < 2; ++ks) {
      bf16x8 af[4], bfv[4];
#pragma unroll
      for (int r = 0; r < 4; ++r) {
        const int ra = r * 16 + r16;            // rows 0..63 (full M-tile)
        af[r] = *(const bf16x8*)((const char*)&Asm[0] +
                ((ra * 128 + ks * 64 + c16 * 16) ^ ((ra & 7) << 4)));
        const int rbn = w * 64 + r * 16 + r16;  // own 64-col half of B
        bfv[r] = *(const bf16x8*)((const char*)&Bsm[0] +
                ((rbn * 128 + ks * 64 + c16 * 16) ^ ((rbn & 7) << 4)));
      }
#pragma unroll
      for (int r = 0; r < 4; ++r)
#pragma unroll
        for (int c = 0; c < 4; ++c)
          acc[r][c] = __builtin_amdgcn_mfma_f32_16x16x32_bf16(
              af[r], bfv[c], acc[r][c], 0, 0, 0);
    }
    __syncthreads();
    if (kt + 1 < nk) stage(kt + 1);
    __syncthreads();
  }

#pragma unroll
  for (int r = 0; r < 4; ++r)
#pragma unroll
    for (int c = 0; c < 4; ++c)
#pragma unroll
      for (int b = 0; b < 4; ++b) {
        const int row = m0 + r * 16 + 4 * c16 + b;
        const int col = n0 + w * 64 + c * 16 + r16;
        fo[(size_t)row * N + col] = acc[r][c][b];
      }
}

// Flash attention, ALiBi + causal. Round-10: exact round-3 structure and
// block mapping (yb->head LPT, x->work item; round-9's XCD affinity cut
// FETCH 37->8MB but cost time — latency-bound, not BW-bound, and the
// reordered dispatch hurt the drain tail). Single delta vs round-3: V is
// staged from the TILED V^T layout (contiguous 8KB/tile reads instead of
// 64 rows at 4KB stride — the read-side channel camping measured in r6/r8).
// Same staged values and accumulation order -> bit-identical numerics.
__global__ __launch_bounds__(256, 5) void attn_part(const u16* __restrict__ qb,
                                                    const u16* __restrict__ kb,
                                                    const u16* __restrict__ vtb,
                                                    u16* __restrict__ ob,
                                                    u16* __restrict__ Op,
                                                    float* __restrict__ ml) {
  __shared__ __align__(16) u16 Kl[2][64 * 64];  // [key][hd], swizzled
  __shared__ __align__(16) u16 Vt[2][64 * 64];  // [hd][key], swizzled

  const int tid = threadIdx.x;
  const int lane = tid & 63, w = tid >> 6;
  const int lo = lane & 15, hi = lane >> 4;
  const int yb = blockIdx.y;
  const int h = 15 - (yb >> 1), bi = yb & 1;   // LPT: heavy heads first
  const int bh = bi * 16 + h;
  const int y = blockIdx.x;                     // work item; XCD = x%8

  int qt, t0, t1, slot = 0;
  bool part;
  if (y < 16) {           // chunk1 of qt = 31-y  (len 9..16, has diag)
    qt = 31 - y;
    const int T = qt + 1;
    t0 = T >> 1; t1 = T; part = true;
    slot = bh * 32 + (qt - 16) * 2 + 1;
  } else if (y < 32) {    // chunk0 of qt = 47-y  (len 8..16)
    qt = 47 - y;
    const int T = qt + 1;
    t0 = 0; t1 = T >> 1; part = true;
    slot = bh * 32 + (qt - 16) * 2;
  } else {                // direct qt = 47-y     (len 1..16)
    qt = 47 - y;
    t0 = 0; t1 = qt + 1; part = false;
  }

  const int q0 = qt * 64;
  const float slope2 = exp2f(-0.5f * (float)(h + 1)) * 1.44269504089f;
  const float s64 = slope2 * 64.f;

  const int Dt = min(32, (int)ceilf(34.f / s64));
  t1 = min(t1, Dt);

  if (part && t0 >= t1) {
#pragma unroll
    for (int g = 0; g < 4; ++g)
#pragma unroll
      for (int r = 0; r < 4; ++r) {
        const int sl = w * 16 + 4 * hi + r;
        Op[(size_t)slot * 4096 + sl * 64 + g * 16 + lo] = 0;
      }
    if (hi == 0) ml[slot * 64 + w * 16 + lo] = 0.f;
    return;
  }

  const u16* __restrict__ Q = qb + (size_t)bh * 131072;
  const u16* __restrict__ Kp = kb + (size_t)bh * 131072;
  const u16* __restrict__ Vp = vtb + (size_t)bh * 131072;

  auto stageK = [&](int t, int buf) {
#pragma unroll
    for (int i = 0; i < 2; ++i) {
      const int chunk = w * 2 + i;
      const int lb = chunk * 1024 + lane * 16;
      const int row = lb >> 7;
      const int rb = (lb & 127) ^ ((row & 7) << 4);
      gload_lds16(Kp + (size_t)(t * 64 + row) * 64 + (rb >> 1),
                  (char*)&Kl[buf][0] + chunk * 1024);
    }
  };
  // V from tiled V^T: tile t is 8KB contiguous [hd][128B keys] — stage is
  // a fully contiguous copy (pre-swizzled source, rule #21).
  auto stageV = [&](int t, int buf) {
#pragma unroll
    for (int i = 0; i < 2; ++i) {
      const int chunk = w * 2 + i;
      const int lb = chunk * 1024 + lane * 16;
      const int row = lb >> 7;  // = hd
      const int rb = (lb & 127) ^ ((row & 7) << 4);
      gload_lds16(Vp + (size_t)t * 4096 + row * 64 + (rb >> 1),
                  (char*)&Vt[buf][0] + chunk * 1024);
    }
  };

  bf16x8 qf[2];
  {
    const u16* qsrc = Q + (size_t)(q0 + w * 16 + lo) * 64 + hi * 8;
    qf[0] = *(const bf16x8*)qsrc;
    qf[1] = *(const bf16x8*)(qsrc + 32);
  }

  const f32x4 zero4 = {0.f, 0.f, 0.f, 0.f};
  f32x4 oacc[4];
#pragma unroll
  for (int g = 0; g < 4; ++g) oacc[g] = zero4;
  float lsum = 0.f;

  float KC[4][4];
#pragma unroll
  for (int g = 0; g < 4; ++g)
#pragma unroll
    for (int r = 0; r < 4; ++r)
      KC[g][r] = slope2 * (float)(16 * g + 4 * hi + r);
  float ctv = 0.f;

  stageK(t0, 0);
  stageV(t0, 0);
  __syncthreads();

  for (int t = t0; t < t1; ++t) {
    const int cur = (t - t0) & 1, nxt = cur ^ 1;
    if (t + 1 < t1) {
      stageK(t + 1, nxt);
      stageV(t + 1, nxt);
    }

    f32x4 st[4];
#pragma unroll
    for (int g = 0; g < 4; ++g) {
#pragma unroll
      for (int r = 0; r < 4; ++r) st[g][r] = ctv - KC[g][r];
#pragma unroll
      for (int ks = 0; ks < 2; ++ks) {
        const int krow = g * 16 + lo;
        const bf16x8 kf = *(const bf16x8*)((const char*)&Kl[cur][0] +
            ((krow * 128 + ks * 64 + hi * 16) ^ ((krow & 7) << 4)));
        st[g] = __builtin_amdgcn_mfma_f32_16x16x32_bf16(kf, qf[ks], st[g], 0, 0, 0);
      }
    }

    if (t == qt) {
#pragma unroll
      for (int g = 0; g < 4; ++g)
#pragma unroll
        for (int r = 0; r < 4; ++r)
          if (g * 16 + 4 * hi + r > w * 16 + lo) st[g][r] = -1e30f;
    }
    float p[4][4];
    float rs = 0.f;
#pragma unroll
    for (int g = 0; g < 4; ++g)
#pragma unroll
      for (int r = 0; r < 4; ++r) {
        p[g][r] = exp2f(st[g][r]);
        rs += p[g][r];
      }
    lsum += rs;

    u32 pk[4][2];
#pragma unroll
    for (int g = 0; g < 4; ++g)
#pragma unroll
      for (int c = 0; c < 2; ++c)
        pk[g][c] = __builtin_amdgcn_perm(
            __builtin_bit_cast(u32, p[g][2 * c + 1]),
            __builtin_bit_cast(u32, p[g][2 * c]), 0x07060302u);

    // P-repack via permlane swaps (round-3 proven lane-exact).
    bf16x8 pA[2];
#pragma unroll
    for (int u = 0; u < 2; ++u) {
      u32 x0 = pk[2 * u][0], x1 = pk[2 * u][1];
      u32 y0 = pk[2 * u + 1][0], y1 = pk[2 * u + 1][1];
      asm("v_permlane32_swap_b32 %0, %1" : "+v"(x0), "+v"(y0));
      asm("v_permlane32_swap_b32 %0, %1" : "+v"(x1), "+v"(y1));
      asm("v_permlane16_swap_b32 %0, %1" : "+v"(x0), "+v"(y0));
      asm("v_permlane16_swap_b32 %0, %1" : "+v"(x1), "+v"(y1));
      u32x4 wv;
      wv.x = x0;
      wv.y = x1;
      wv.z = y0;
      wv.w = y1;
      pA[u] = __builtin_bit_cast(bf16x8, wv);
    }

#pragma unroll
    for (int g = 0; g < 4; ++g) {
#pragma unroll
      for (int u = 0; u < 2; ++u) {
        const int vrow = g * 16 + lo;
        const bf16x8 vf = *(const bf16x8*)((const char*)&Vt[cur][0] +
            ((vrow * 128 + u * 64 + hi * 16) ^ ((vrow & 7) << 4)));
        oacc[g] = __builtin_amdgcn_mfma_f32_16x16x32_bf16(pA[u], vf, oacc[g], 0, 0, 0);
      }
    }

    ctv -= s64;
    __syncthreads();
  }

  lsum += __shfl_xor(lsum, 16, 64);
  lsum += __shfl_xor(lsum, 32, 64);
  const float inv = 1.f / lsum;
  float iv[4];
#pragma unroll
  for (int r = 0; r < 4; ++r) iv[r] = __shfl(inv, 4 * hi + r, 64);

  if (!part) {
#pragma unroll
    for (int g = 0; g < 4; ++g)
#pragma unroll
      for (int r = 0; r < 4; ++r) {
        const int s = q0 + w * 16 + 4 * hi + r;
        const int hd = g * 16 + lo;
        ob[(((size_t)bi * 2048 + s) * 16 + h) * 64 + hd] =
            f2bf(oacc[g][r] * iv[r]);
      }
  } else {
#pragma unroll
    for (int g = 0; g < 4; ++g)
#pragma unroll
      for (int r = 0; r < 4; ++r) {
        const int sl = w * 16 + 4 * hi + r;
        Op[(size_t)slot * 4096 + sl * 64 + g * 16 + lo] =
            f2bf(oacc[g][r] * iv[r]);
      }
    if (hi == 0) ml[slot * 64 + w * 16 + lo] = lsum;
  }
}

// Merge the two chunk partials for q-tiles 16..31 (analytic chunk weights:
// w0 = l0, w1 = l1 * exp2(-slope2*64*t0)). Pruned chunk1: l1 = 0 -> 0.
__global__ __launch_bounds__(256) void attn_comb(const u16* __restrict__ Op,
                                                 const float* __restrict__ ml,
                                                 u16* __restrict__ ob) {
  const int bh = blockIdx.x, q16 = blockIdx.y;
  const int h = bh & 15, bi = bh >> 4;
  const int qt = 16 + q16;
  const int t0c = (qt + 1) >> 1;
  const float slope2 = exp2f(-0.5f * (float)(h + 1)) * 1.44269504089f;
  const float e1 = exp2f(-slope2 * 64.f * (float)t0c);
  const int slot0 = bh * 32 + q16 * 2;
  const int row = threadIdx.x >> 2, c0 = (threadIdx.x & 3) * 16;
  const float l0 = ml[slot0 * 64 + row];
  const float l1 = ml[(slot0 + 1) * 64 + row];
  const float w0 = l0, w1 = l1 * e1;
  const float inv = 1.f / (w0 + w1);
  const float a0 = w0 * inv, a1 = w1 * inv;
  const u16* p0 = Op + (size_t)slot0 * 4096 + row * 64 + c0;
  const u16* p1 = p0 + 4096;
  u32 A0[8], A1[8];
  *(uint4*)&A0[0] = *(const uint4*)p0;
  *(uint4*)&A0[4] = *(const uint4*)(p0 + 8);
  *(uint4*)&A1[0] = *(const uint4*)p1;
  *(uint4*)&A1[4] = *(const uint4*)(p1 + 8);
  const int s = qt * 64 + row;
  u32* dst = (u32*)(ob + (((size_t)bi * 2048 + s) * 16 + h) * 64 + c0);
#pragma unroll
  for (int j = 0; j < 8; ++j) {
    const float e0 = a0 * bf2f((u16)(A0[j] & 0xffffu)) +
                     a1 * bf2f((u16)(A1[j] & 0xffffu));
    const float ee1 = a0 * bf2f((u16)(A0[j] >> 16)) +
                      a1 * bf2f((u16)(A1[j] >> 16));
    dst[j] = (u32)f2bf(e0) | ((u32)f2bf(ee1) << 16);
  }
}

extern "C" void kernel_launch(void* const* d_in, const int* in_sizes, int n_in,
                              void* d_out, int out_size, void* d_ws, size_t ws_size,
                              hipStream_t stream) {
  const float* x = (const float*)d_in[0];     // (2,2048,1024)
  const float* Wqkv = (const float*)d_in[1];  // (3072,1024)
  const float* Wo = (const float*)d_in[2];    // (1024,1024)
  float* out = (float*)d_out;                 // (2,2048,1024) fp32

  // workspace layout (u16 elements)
  u16* xb  = (u16*)d_ws;        // x bf16          4194304  | reused: O partials
  u16* wqb = xb + 4194304;      // W_qkv bf16      3145728  | reused: l partials
  u16* wob = wqb + 3145728;     // W_o bf16        1048576
  u16* qbf = wob + 1048576;     // q (b,h,s,hd), pre-scaled  4194304
  u16* kbf = qbf + 4194304;     // k (b,h,s,hd)    4194304
  u16* vbf = kbf + 4194304;     // v^T tiled (b,h,s/64,hd,64)  4194304
  u16* abf = vbf + 4194304;     // attn out (b,s,h,hd) 4194304

  u16* Op = xb;                 // 1024 slots x 4096 u16 (normalized O, bf16)
  float* ml = (float*)wqb;      // 1024 slots x 64 f32 (l per row)

  cvt_all<<<8192, 256, 0, stream>>>(x, Wqkv, Wo, xb, wqb, wob);

  gemm_qkv<<<dim3(24, 32), 256, 0, stream>>>(xb, wqb, 1024, qbf, kbf, vbf);
  attn_part<<<dim3(48, 32), 256, 0, stream>>>(qbf, kbf, vbf, abf, Op, ml);
  attn_comb<<<dim3(32, 16), 256, 0, stream>>>(Op, ml, abf);
  // 64x128 tile, 512 blocks = 2/CU (fills the machine; W_o L2-resident)
  gemm_proj<<<dim3(8, 64), 128, 0, stream>>>(abf, wob, 1024, 1024, out);
}